// Round 5
// baseline (1179.717 us; speedup 1.0000x reference)
//
#include <hip/hip_runtime.h>
#include <cstdint>
#include <cstddef>

#define B_GRAPHS 32
#define NPG      8192
#define N_NODES  (B_GRAPHS * NPG)   // 262144
#define DEG      8
#define NE       (N_NODES * DEG)    // 2097152
#define N1       32768              // B * 32*32  (grid 4)
#define N2       8192               // B * 16*16  (grid 8)
#define BKT_CAP  80

// ---------------------------------------------------------------------------
// Node-level precompute: a[i,o] = b[o] + sum_k h[i,k]*W[k,o] + px*W[IN,o] + py*W[IN+1,o]
// ---------------------------------------------------------------------------
template<int IN, int OUT>
__global__ __launch_bounds__(256)
void node_a_kernel(const float* __restrict__ h, const float* __restrict__ pos,
                   const float* __restrict__ W, const float* __restrict__ bias,
                   float* __restrict__ a, int n) {
    constexpr int FEAT = IN + 2;
    __shared__ float Ws[FEAT * OUT + OUT];
    for (int i = threadIdx.x; i < FEAT * OUT; i += 256) Ws[i] = W[i];
    for (int i = threadIdx.x; i < OUT; i += 256) Ws[FEAT * OUT + i] = bias[i];
    __syncthreads();
    int i = blockIdx.x * 256 + threadIdx.x;
    if (i >= n) return;

    float acc[OUT];
    #pragma unroll
    for (int o = 0; o < OUT; ++o) acc[o] = Ws[FEAT * OUT + o];

    float px = pos[i * 3 + 0], py = pos[i * 3 + 1];
    #pragma unroll
    for (int o = 0; o < OUT; ++o)
        acc[o] += px * Ws[IN * OUT + o] + py * Ws[(IN + 1) * OUT + o];

    if constexpr (IN % 4 == 0) {
        const float4* h4 = (const float4*)(h + (size_t)i * IN);
        for (int k4 = 0; k4 < IN / 4; ++k4) {
            float4 f = h4[k4];
            #pragma unroll
            for (int o = 0; o < OUT; ++o) {
                acc[o] += f.x * Ws[(k4 * 4 + 0) * OUT + o];
                acc[o] += f.y * Ws[(k4 * 4 + 1) * OUT + o];
                acc[o] += f.z * Ws[(k4 * 4 + 2) * OUT + o];
                acc[o] += f.w * Ws[(k4 * 4 + 3) * OUT + o];
            }
        }
    } else {
        for (int k = 0; k < IN; ++k) {
            float f = h[(size_t)i * IN + k];
            #pragma unroll
            for (int o = 0; o < OUT; ++o) acc[o] += f * Ws[k * OUT + o];
        }
    }
    float* ap = a + (size_t)i * OUT;
    #pragma unroll
    for (int o = 0; o < OUT; ++o) ap[o] = acc[o];
}

// ---------------------------------------------------------------------------
// Per-graph edge histogram (gcnt must be zeroed) + serial 32-entry scan.
// ---------------------------------------------------------------------------
__global__ __launch_bounds__(256)
void precount_kernel(const int* __restrict__ dst, int* __restrict__ gcnt) {
    __shared__ int hist[B_GRAPHS];
    if (threadIdx.x < B_GRAPHS) hist[threadIdx.x] = 0;
    __syncthreads();
    int gid = blockIdx.x * 256 + threadIdx.x;
    for (int e = gid; e < NE; e += 256 * 256)
        atomicAdd(&hist[dst[e] >> 13], 1);
    __syncthreads();
    if (threadIdx.x < B_GRAPHS) atomicAdd(&gcnt[threadIdx.x], hist[threadIdx.x]);
}

__global__ void gscan_kernel(const int* __restrict__ gcnt, int* __restrict__ gbase,
                             int* __restrict__ gcur) {
    if (threadIdx.x == 0) {
        int run = 0;
        for (int g = 0; g < B_GRAPHS; ++g) {
            gbase[g] = run; gcur[g] = run;
            run += gcnt[g];
        }
        gbase[B_GRAPHS] = run;
    }
}

// ---------------------------------------------------------------------------
// Bucket edges by graph into graph-major (src,dst) pairs. Coalesced flushes.
// ---------------------------------------------------------------------------
__global__ __launch_bounds__(256)
void bucket_kernel(const int* __restrict__ src, const int* __restrict__ dst,
                   int* __restrict__ gcur, int2* __restrict__ binned) {
    __shared__ int2 bins[B_GRAPHS][BKT_CAP];
    __shared__ int bcnt[B_GRAPHS], sbase[B_GRAPHS], sn[B_GRAPHS];
    int tid = threadIdx.x;
    if (tid < B_GRAPHS) bcnt[tid] = 0;
    __syncthreads();
    int wgbase = blockIdx.x * 2048;
    for (int sub = 0; sub < 2; ++sub) {
        int e0 = wgbase + sub * 1024 + tid * 4;
        int4 s4 = *(const int4*)&src[e0];
        int4 d4 = *(const int4*)&dst[e0];
        int ss[4] = {s4.x, s4.y, s4.z, s4.w};
        int dd[4] = {d4.x, d4.y, d4.z, d4.w};
        #pragma unroll
        for (int k = 0; k < 4; ++k) {
            int b = dd[k] >> 13;
            int pos = atomicAdd(&bcnt[b], 1);
            if (pos < BKT_CAP) bins[b][pos] = make_int2(ss[k], dd[k]);
            else { int gp = atomicAdd(&gcur[b], 1); binned[gp] = make_int2(ss[k], dd[k]); }
        }
        __syncthreads();
        if (tid < B_GRAPHS) {
            int nb = min(bcnt[tid], BKT_CAP);
            sn[tid] = nb;
            sbase[tid] = atomicAdd(&gcur[tid], nb);
        }
        __syncthreads();
        int b = tid >> 3, r = tid & 7;
        for (int k = r; k < sn[b]; k += 8) binned[sbase[b] + k] = bins[b][k];
        __syncthreads();
        if (tid < B_GRAPHS) bcnt[tid] = 0;
        __syncthreads();
    }
}

// ---------------------------------------------------------------------------
// Per-graph CSR build at level A (one wg per graph; csr writes XCD-local).
// ---------------------------------------------------------------------------
__global__ __launch_bounds__(1024)
void csrA_kernel(const int2* __restrict__ binned, const int* __restrict__ gbase,
                 const int* __restrict__ gend,
                 int* __restrict__ lo, int* __restrict__ hi, int* __restrict__ csr) {
    __shared__ int cnt[NPG];
    __shared__ int aux[1024];
    int g = blockIdx.x, t = threadIdx.x;
    for (int i = t; i < NPG; i += 1024) cnt[i] = 0;
    __syncthreads();
    int segb = gbase[g], sege = gend[g];
    int nodeb = g * NPG;
    for (int e = segb + t; e < sege; e += 1024)
        atomicAdd(&cnt[binned[e].y - nodeb], 1);
    __syncthreads();
    int c[8], sum = 0;
    #pragma unroll
    for (int k = 0; k < 8; ++k) { c[k] = cnt[t * 8 + k]; sum += c[k]; }
    aux[t] = sum;
    __syncthreads();
    for (int d = 1; d < 1024; d <<= 1) {
        int v = (t >= d) ? aux[t - d] : 0;
        __syncthreads();
        aux[t] += v;
        __syncthreads();
    }
    int run = segb + aux[t] - sum;
    #pragma unroll
    for (int k = 0; k < 8; ++k) {
        int i = nodeb + t * 8 + k;
        lo[i] = run; hi[i] = run + c[k];
        cnt[t * 8 + k] = run;
        run += c[k];
    }
    __syncthreads();
    for (int e = segb + t; e < sege; e += 1024) {
        int2 sd = binned[e];
        int p = atomicAdd(&cnt[sd.y - nodeb], 1);
        csr[p] = sd.x;
    }
}

// ---------------------------------------------------------------------------
// Hierarchical exclusive scan over counts (n % 1024 == 0), writes offsets+cursor.
// ---------------------------------------------------------------------------
__global__ __launch_bounds__(256)
void scan_reduce_kernel(const int* __restrict__ counts, int* __restrict__ blocksums) {
    int t = threadIdx.x;
    int4 v = *(const int4*)&counts[blockIdx.x * 1024 + t * 4];
    int s = v.x + v.y + v.z + v.w;
    #pragma unroll
    for (int off = 32; off > 0; off >>= 1) s += __shfl_xor(s, off, 64);
    __shared__ int ws[4];
    if ((t & 63) == 0) ws[t >> 6] = s;
    __syncthreads();
    if (t == 0) blocksums[blockIdx.x] = ws[0] + ws[1] + ws[2] + ws[3];
}

__global__ __launch_bounds__(256)
void scan_blocks_kernel(const int* __restrict__ blocksums, int* __restrict__ blockpref,
                        int* __restrict__ offsets, int nb, int n) {
    __shared__ int sh[256];
    int t = threadIdx.x;
    int v = (t < nb) ? blocksums[t] : 0;
    sh[t] = v;
    __syncthreads();
    #pragma unroll
    for (int d = 1; d < 256; d <<= 1) {
        int u = (t >= d) ? sh[t - d] : 0;
        __syncthreads();
        sh[t] += u;
        __syncthreads();
    }
    if (t < nb) blockpref[t] = sh[t] - v;
    if (t == 255) offsets[n] = sh[255];
}

__global__ __launch_bounds__(256)
void scan_write_kernel(const int* __restrict__ counts, const int* __restrict__ blockpref,
                       int* __restrict__ offsets, int* __restrict__ cursor) {
    int b = blockIdx.x, t = threadIdx.x;
    int base = b * 1024 + t * 4;
    int4 v = *(const int4*)&counts[base];
    int s = v.x + v.y + v.z + v.w;
    __shared__ int sh[256];
    sh[t] = s;
    __syncthreads();
    #pragma unroll
    for (int d = 1; d < 256; d <<= 1) {
        int u = (t >= d) ? sh[t - d] : 0;
        __syncthreads();
        sh[t] += u;
        __syncthreads();
    }
    int pref = blockpref[b] + sh[t] - s;
    int4 o;
    o.x = pref;
    o.y = pref + v.x;
    o.z = o.y + v.y;
    o.w = o.z + v.z;
    *(int4*)&offsets[base] = o;
    *(int4*)&cursor[base] = o;
}

// ---------------------------------------------------------------------------
// Gather-max conv at level A: wave per dst node; fused pool1 (atomicMax, >=0).
// ---------------------------------------------------------------------------
template<int OUT>
__global__ __launch_bounds__(256)
void gatherw_kernel(const float* __restrict__ a, const float* __restrict__ pos,
                    const float* __restrict__ Wp,
                    const int* __restrict__ lo, const int* __restrict__ hi,
                    const int* __restrict__ csr, const int* __restrict__ cluster,
                    float* __restrict__ out, int n) {
    constexpr int G = 64 / OUT;
    int wave = (blockIdx.x * 256 + threadIdx.x) >> 6;
    int lane = threadIdx.x & 63;
    int ch = lane % OUT, grp = lane / OUT;
    if (wave >= n) return;
    int l = lo[wave], h = hi[wave];
    float m = -1e30f;
    for (int j = l + grp; j < h; j += G)
        m = fmaxf(m, a[(size_t)csr[j] * OUT + ch]);
    #pragma unroll
    for (int st = OUT; st < 64; st <<= 1)
        m = fmaxf(m, __shfl_xor(m, st, 64));
    float px = pos[wave * 3 + 0], py = pos[wave * 3 + 1];
    float cterm = px * Wp[ch] + py * Wp[OUT + ch];
    float val = (h > l) ? fmaxf(m - cterm, 0.0f) : 0.0f;
    if (grp == 0 && val > 0.0f)
        atomicMax((int*)&out[(size_t)cluster[wave] * OUT + ch], __float_as_int(val));
}

// ---------------------------------------------------------------------------
// Coarse-level conv: block per coarse node v; iterate member old nodes' A-level
// edge spans; per-edge source cluster from ecl (composed through c2map if set).
// Self-loops (sc == v) skipped. MODE 0: store; MODE 1: atomicMax out[outmap[v]].
// ---------------------------------------------------------------------------
template<int OUT, int MODE>
__global__ __launch_bounds__(256)
void gmemb_kernel(const float* __restrict__ a, const float* __restrict__ pos,
                  const float* __restrict__ Wp,
                  const int* __restrict__ moff, const int* __restrict__ memb,
                  const int* __restrict__ loA, const int* __restrict__ hiA,
                  const int* __restrict__ ecl, const int* __restrict__ c2map,
                  const int* __restrict__ outmap, float* __restrict__ out) {
    constexpr int STREAMS = 256 / OUT;
    int v = blockIdx.x;
    int tid = threadIdx.x;
    int ch = tid % OUT, s = tid / OUT;
    int mo = moff[v], me = moff[v + 1];
    float m = -1e30f;
    for (int mi = mo + s; mi < me; mi += STREAMS) {
        int node = memb[mi];
        int l = loA[node], h = hiA[node];
        for (int j = l; j < h; ++j) {
            int sc = ecl[j];
            if (c2map) sc = c2map[sc];
            if (sc == v) continue;
            m = fmaxf(m, a[(size_t)sc * OUT + ch]);
        }
    }
    __shared__ float sh[256];
    sh[tid] = m;
    __syncthreads();
    if (tid < OUT) {
        #pragma unroll
        for (int k = 1; k < STREAMS; ++k) m = fmaxf(m, sh[k * OUT + tid]);
        float px = pos[v * 3 + 0], py = pos[v * 3 + 1];
        float cterm = px * Wp[tid] + py * Wp[OUT + tid];
        float val = (m > -1e29f) ? fmaxf(m - cterm, 0.0f) : 0.0f;
        if (MODE == 0) out[(size_t)v * OUT + tid] = val;
        else if (val > 0.0f)
            atomicMax((int*)&out[(size_t)outmap[v] * OUT + tid], __float_as_int(val));
    }
}

// ---------------------------------------------------------------------------
// Voxel cluster id + pos mean accumulation (int counts); finalize; out-cells.
// ---------------------------------------------------------------------------
__global__ __launch_bounds__(256)
void cluster_kernel(const float* __restrict__ pos, int* __restrict__ cluster,
                    float* __restrict__ psum, int* __restrict__ cnt,
                    int n, int batch_shift, float inv_grid, int cells) {
    int i = blockIdx.x * 256 + threadIdx.x;
    if (i >= n) return;
    float px = pos[i * 3 + 0], py = pos[i * 3 + 1], pz = pos[i * 3 + 2];
    int ix = min(max((int)floorf(px * inv_grid), 0), cells - 1);
    int iy = min(max((int)floorf(py * inv_grid), 0), cells - 1);
    int c = (i >> batch_shift) * cells * cells + iy * cells + ix;
    cluster[i] = c;
    atomicAdd(&psum[c * 3 + 0], px);
    atomicAdd(&psum[c * 3 + 1], py);
    atomicAdd(&psum[c * 3 + 2], pz);
    atomicAdd(&cnt[c], 1);
}

__global__ __launch_bounds__(256)
void posfin_kernel(const float* __restrict__ pos_sum, const int* __restrict__ cnt,
                   float* __restrict__ pos_new, int n_new) {
    int i = blockIdx.x * 256 + threadIdx.x;
    if (i >= n_new) return;
    float c = fmaxf((float)cnt[i], 1.0f);
    pos_new[i * 3 + 0] = pos_sum[i * 3 + 0] / c;
    pos_new[i * 3 + 1] = pos_sum[i * 3 + 1] / c;
    pos_new[i * 3 + 2] = pos_sum[i * 3 + 2] / c;
}

__global__ __launch_bounds__(256)
void cellout_kernel(const float* __restrict__ pos, int* __restrict__ cell, int n) {
    int i = blockIdx.x * 256 + threadIdx.x;
    if (i >= n) return;
    float px = pos[i * 3 + 0], py = pos[i * 3 + 1];
    int ix = min(max((int)floorf(px * (1.0f / 16.0f)), 0), 7);
    int iy = min(max((int)floorf(py * (1.0f / 16.0f)), 0), 7);
    cell[i] = (i >> 8) * 64 + iy * 8 + ix;
}

// per-edge source-cluster map at level B
__global__ __launch_bounds__(256)
void edgemap_kernel(const int* __restrict__ csr, const int* __restrict__ c1,
                    int* __restrict__ c1s) {
    int j = blockIdx.x * 256 + threadIdx.x;
    if (j < NE) c1s[j] = c1[csr[j]];
}

// count old nodes per composed (level-C) cluster
__global__ __launch_bounds__(256)
void cnt12_kernel(const int* __restrict__ c1, const int* __restrict__ c2,
                  int* __restrict__ icnt12) {
    int i = blockIdx.x * 256 + threadIdx.x;
    if (i < N_NODES) atomicAdd(&icnt12[c2[c1[i]]], 1);
}

// fill both membership lists
__global__ __launch_bounds__(256)
void membfill_kernel(const int* __restrict__ c1, const int* __restrict__ c2,
                     int* __restrict__ mcur1, int* __restrict__ memb1,
                     int* __restrict__ mcur12, int* __restrict__ memb12) {
    int i = blockIdx.x * 256 + threadIdx.x;
    if (i >= N_NODES) return;
    int v1 = c1[i];
    int p = atomicAdd(&mcur1[v1], 1);
    memb1[p] = i;
    int w = c2[v1];
    int q = atomicAdd(&mcur12[w], 1);
    memb12[q] = i;
}

// ---------------------------------------------------------------------------
// MLP head
// ---------------------------------------------------------------------------
__global__ __launch_bounds__(256)
void mlp1_kernel(const float* __restrict__ g, const float* __restrict__ Wl1,
                 float* __restrict__ hid) {
    int b = blockIdx.x, kc = blockIdx.y, t = threadIdx.x;
    const float* grow = g + (size_t)b * 4096;
    int o0 = t * 4;
    float a0 = 0, a1 = 0, a2 = 0, a3 = 0;
    int k0 = kc * 512;
    for (int k = k0; k < k0 + 512; ++k) {
        float gk = grow[k];
        float4 w = *(const float4*)&Wl1[(size_t)k * 1024 + o0];
        a0 += gk * w.x; a1 += gk * w.y; a2 += gk * w.z; a3 += gk * w.w;
    }
    float* hp = hid + (size_t)b * 1024 + o0;
    atomicAdd(hp + 0, a0);
    atomicAdd(hp + 1, a1);
    atomicAdd(hp + 2, a2);
    atomicAdd(hp + 3, a3);
}

__global__ __launch_bounds__(64)
void mlp2_kernel(const float* __restrict__ hid, const float* __restrict__ bl1,
                 const float* __restrict__ Wl2, const float* __restrict__ bl2,
                 float* __restrict__ out) {
    int b = blockIdx.x, l = threadIdx.x;
    float hv[16];
    #pragma unroll
    for (int i = 0; i < 16; ++i) {
        int idx = l + i * 64;
        hv[i] = fmaxf(hid[(size_t)b * 1024 + idx] + bl1[idx], 0.0f);
    }
    float logits[10];
    #pragma unroll
    for (int c = 0; c < 10; ++c) {
        float p = 0.0f;
        #pragma unroll
        for (int i = 0; i < 16; ++i)
            p += hv[i] * Wl2[(size_t)(l + i * 64) * 10 + c];
        #pragma unroll
        for (int off = 32; off > 0; off >>= 1) p += __shfl_xor(p, off, 64);
        logits[c] = p + bl2[c];
    }
    float m = logits[0];
    #pragma unroll
    for (int c = 1; c < 10; ++c) m = fmaxf(m, logits[c]);
    float ssum = 0.0f;
    #pragma unroll
    for (int c = 0; c < 10; ++c) ssum += expf(logits[c] - m);
    float lse = logf(ssum);
    if (l < 10) out[b * 10 + l] = logits[l] - m - lse;
}

// ---------------------------------------------------------------------------
extern "C" void kernel_launch(void* const* d_in, const int* in_sizes, int n_in,
                              void* d_out, int out_size, void* d_ws, size_t ws_size,
                              hipStream_t stream) {
    const float* x    = (const float*)d_in[0];
    const float* pos0 = (const float*)d_in[1];
    const int*   ei   = (const int*)d_in[2];
    const float* W1 = (const float*)d_in[4];  const float* b1 = (const float*)d_in[5];
    const float* W2 = (const float*)d_in[6];  const float* b2 = (const float*)d_in[7];
    const float* W3 = (const float*)d_in[8];  const float* b3 = (const float*)d_in[9];
    const float* W4 = (const float*)d_in[10]; const float* b4 = (const float*)d_in[11];
    const float* W5 = (const float*)d_in[12]; const float* b5 = (const float*)d_in[13];
    const float* Wl1 = (const float*)d_in[14]; const float* bl1 = (const float*)d_in[15];
    const float* Wl2 = (const float*)d_in[16]; const float* bl2 = (const float*)d_in[17];
    const int* src0 = ei;
    const int* dst0 = ei + NE;
    float* out = (float*)d_out;

    float* w = (float*)d_ws;
    size_t off = 0;
    auto alloc = [&](size_t n) { float* p = w + off; off += n; return p; };

    // --- zero-init region (one memset) ---
    int*   gcnt   = (int*)alloc(32);
    float* hp1    = alloc((size_t)N1 * 16);
    float* psum1  = alloc((size_t)N1 * 3);
    int*   icnt1  = (int*)alloc(N1);
    float* hp2    = alloc((size_t)N2 * 32);
    float* psum2  = alloc((size_t)N2 * 3);
    int*   icnt2  = (int*)alloc(N2);
    int*   icnt12 = (int*)alloc(N2);
    float* g      = alloc((size_t)B_GRAPHS * 4096);
    float* hid    = alloc((size_t)B_GRAPHS * 1024);
    size_t zero_bytes = off * sizeof(float);
    // --- abuf (a at every level) ---
    float* abuf = alloc((size_t)N_NODES * 16);
    // --- union: binned (level A build only) overlaps later buffers ---
    float* ubase = alloc((size_t)NE * 2);                   // 4.19M floats
    int2*  binned = (int2*)ubase;
    float* h2   = ubase;                                    // N1*32
    float* h4   = h2 + (size_t)N1 * 32;                     // N2*64
    float* pos2 = h4 + (size_t)N2 * 64;                     // N2*3
    int*   cell = (int*)(pos2 + (size_t)N2 * 3);            // N2
    int*   c1s  = cell + N2;                                // NE
    // --- rest ---
    int* csr0 = (int*)alloc(NE);
    int* loA  = (int*)alloc(N_NODES);
    int* hiA  = (int*)alloc(N_NODES);
    float* pos1 = alloc((size_t)N1 * 3);
    int* c1   = (int*)alloc(N_NODES);
    int* c2   = (int*)alloc(N1);
    int* moff1  = (int*)alloc(N1 + 4);
    int* mcur1  = (int*)alloc(N1);
    int* moff12 = (int*)alloc(N2 + 4);
    int* mcur12 = (int*)alloc(N2);
    int* memb1  = (int*)alloc(N_NODES);
    int* memb12 = (int*)alloc(N_NODES);
    int* gbase = (int*)alloc(64);
    int* gcur  = (int*)alloc(64);
    int* blocksums = (int*)alloc(512);
    int* blockpref = (int*)alloc(512);
    (void)ws_size; (void)in_sizes; (void)n_in; (void)out_size;

    hipMemsetAsync(d_ws, 0, zero_bytes, stream);

    // ===== level A: CSR build + conv1 (fused pool1) =====
    node_a_kernel<1, 16><<<N_NODES / 256, 256, 0, stream>>>(x, pos0, W1, b1, abuf, N_NODES);
    precount_kernel<<<256, 256, 0, stream>>>(dst0, gcnt);
    gscan_kernel<<<1, 64, 0, stream>>>(gcnt, gbase, gcur);
    bucket_kernel<<<NE / 2048, 256, 0, stream>>>(src0, dst0, gcur, binned);
    csrA_kernel<<<B_GRAPHS, 1024, 0, stream>>>(binned, gbase, gcur, loA, hiA, csr0);
    cluster_kernel<<<N_NODES / 256, 256, 0, stream>>>(pos0, c1, psum1, icnt1, N_NODES, 13, 0.25f, 32);
    gatherw_kernel<16><<<N_NODES / 4, 256, 0, stream>>>(abuf, pos0, W1 + 16,
                                                        loA, hiA, csr0, c1, hp1, N_NODES);
    posfin_kernel<<<N1 / 256, 256, 0, stream>>>(psum1, icnt1, pos1, N1);

    // ===== membership lists + per-edge cluster map (binned dead after csrA) =====
    edgemap_kernel<<<NE / 256, 256, 0, stream>>>(csr0, c1, c1s);
    cluster_kernel<<<N1 / 256, 256, 0, stream>>>(pos1, c2, psum2, icnt2, N1, 10, 0.125f, 16);
    posfin_kernel<<<N2 / 256, 256, 0, stream>>>(psum2, icnt2, pos2, N2);
    cnt12_kernel<<<N_NODES / 256, 256, 0, stream>>>(c1, c2, icnt12);
    scan_reduce_kernel<<<N1 / 1024, 256, 0, stream>>>(icnt1, blocksums);
    scan_blocks_kernel<<<1, 256, 0, stream>>>(blocksums, blockpref, moff1, N1 / 1024, N1);
    scan_write_kernel<<<N1 / 1024, 256, 0, stream>>>(icnt1, blockpref, moff1, mcur1);
    scan_reduce_kernel<<<N2 / 1024, 256, 0, stream>>>(icnt12, blocksums);
    scan_blocks_kernel<<<1, 256, 0, stream>>>(blocksums, blockpref, moff12, N2 / 1024, N2);
    scan_write_kernel<<<N2 / 1024, 256, 0, stream>>>(icnt12, blockpref, moff12, mcur12);
    membfill_kernel<<<N_NODES / 256, 256, 0, stream>>>(c1, c2, mcur1, memb1, mcur12, memb12);

    // ===== level B: conv2 (store), conv3 (fused pool2) =====
    node_a_kernel<16, 32><<<N1 / 256, 256, 0, stream>>>(hp1, pos1, W2, b2, abuf, N1);
    gmemb_kernel<32, 0><<<N1, 256, 0, stream>>>(abuf, pos1, W2 + 512, moff1, memb1,
                                                loA, hiA, c1s, nullptr, nullptr, h2);
    node_a_kernel<32, 32><<<N1 / 256, 256, 0, stream>>>(h2, pos1, W3, b3, abuf, N1);
    gmemb_kernel<32, 1><<<N1, 256, 0, stream>>>(abuf, pos1, W3 + 1024, moff1, memb1,
                                                loA, hiA, c1s, nullptr, c2, hp2);

    // ===== level C: conv4 (store), conv5 (fused pool_out) =====
    node_a_kernel<32, 64><<<N2 / 256, 256, 0, stream>>>(hp2, pos2, W4, b4, abuf, N2);
    gmemb_kernel<64, 0><<<N2, 256, 0, stream>>>(abuf, pos2, W4 + 2048, moff12, memb12,
                                                loA, hiA, c1s, c2, nullptr, h4);
    node_a_kernel<64, 64><<<N2 / 256, 256, 0, stream>>>(h4, pos2, W5, b5, abuf, N2);
    cellout_kernel<<<N2 / 256, 256, 0, stream>>>(pos2, cell, N2);
    gmemb_kernel<64, 1><<<N2, 256, 0, stream>>>(abuf, pos2, W5 + 4096, moff12, memb12,
                                                loA, hiA, c1s, c2, cell, g);

    // ===== MLP head =====
    mlp1_kernel<<<dim3(32, 8), 256, 0, stream>>>(g, Wl1, hid);
    mlp2_kernel<<<32, 64, 0, stream>>>(hid, bl1, Wl2, bl2, out);
}

// Round 6
// 863.894 us; speedup vs baseline: 1.3656x; 1.3656x over previous
//
#include <hip/hip_runtime.h>
#include <cstdint>
#include <cstddef>

#define B_GRAPHS 32
#define NPG      8192
#define N_NODES  (B_GRAPHS * NPG)   // 262144
#define DEG      8
#define NE       (N_NODES * DEG)    // 2097152
#define N1       32768              // B * 32*32  (grid 4)
#define N2       8192               // B * 16*16  (grid 8)
#define BKT_CAP  80

// ---------------------------------------------------------------------------
// Node-level precompute: a[i,o] = b[o] + sum_k h[i,k]*W[k,o] + px*W[IN,o] + py*W[IN+1,o]
// ---------------------------------------------------------------------------
template<int IN, int OUT>
__global__ __launch_bounds__(256)
void node_a_kernel(const float* __restrict__ h, const float* __restrict__ pos,
                   const float* __restrict__ W, const float* __restrict__ bias,
                   float* __restrict__ a, int n) {
    constexpr int FEAT = IN + 2;
    __shared__ float Ws[FEAT * OUT + OUT];
    for (int i = threadIdx.x; i < FEAT * OUT; i += 256) Ws[i] = W[i];
    for (int i = threadIdx.x; i < OUT; i += 256) Ws[FEAT * OUT + i] = bias[i];
    __syncthreads();
    int i = blockIdx.x * 256 + threadIdx.x;
    if (i >= n) return;

    float acc[OUT];
    #pragma unroll
    for (int o = 0; o < OUT; ++o) acc[o] = Ws[FEAT * OUT + o];

    float px = pos[i * 3 + 0], py = pos[i * 3 + 1];
    #pragma unroll
    for (int o = 0; o < OUT; ++o)
        acc[o] += px * Ws[IN * OUT + o] + py * Ws[(IN + 1) * OUT + o];

    if constexpr (IN % 4 == 0) {
        const float4* h4 = (const float4*)(h + (size_t)i * IN);
        for (int k4 = 0; k4 < IN / 4; ++k4) {
            float4 f = h4[k4];
            #pragma unroll
            for (int o = 0; o < OUT; ++o) {
                acc[o] += f.x * Ws[(k4 * 4 + 0) * OUT + o];
                acc[o] += f.y * Ws[(k4 * 4 + 1) * OUT + o];
                acc[o] += f.z * Ws[(k4 * 4 + 2) * OUT + o];
                acc[o] += f.w * Ws[(k4 * 4 + 3) * OUT + o];
            }
        }
    } else {
        for (int k = 0; k < IN; ++k) {
            float f = h[(size_t)i * IN + k];
            #pragma unroll
            for (int o = 0; o < OUT; ++o) acc[o] += f * Ws[k * OUT + o];
        }
    }
    float* ap = a + (size_t)i * OUT;
    #pragma unroll
    for (int o = 0; o < OUT; ++o) ap[o] = acc[o];
}

// ---------------------------------------------------------------------------
// Per-graph edge histogram (gcnt zeroed) + tiny serial scan.
// ---------------------------------------------------------------------------
__global__ __launch_bounds__(256)
void precount_kernel(const int* __restrict__ dst, int* __restrict__ gcnt) {
    __shared__ int hist[B_GRAPHS];
    if (threadIdx.x < B_GRAPHS) hist[threadIdx.x] = 0;
    __syncthreads();
    int gid = blockIdx.x * 256 + threadIdx.x;
    for (int e = gid; e < NE; e += 256 * 256)
        atomicAdd(&hist[dst[e] >> 13], 1);
    __syncthreads();
    if (threadIdx.x < B_GRAPHS) atomicAdd(&gcnt[threadIdx.x], hist[threadIdx.x]);
}

__global__ void gscan_kernel(const int* __restrict__ gcnt, int* __restrict__ gbase,
                             int* __restrict__ gcur) {
    if (threadIdx.x == 0) {
        int run = 0;
        for (int g = 0; g < B_GRAPHS; ++g) {
            gbase[g] = run; gcur[g] = run;
            run += gcnt[g];
        }
        gbase[B_GRAPHS] = run;
    }
}

// ---------------------------------------------------------------------------
// Bucket edges by graph, packed local (src<<13 | dst). Coalesced flushes.
// ---------------------------------------------------------------------------
__global__ __launch_bounds__(256)
void bucket_kernel(const int* __restrict__ src, const int* __restrict__ dst,
                   int* __restrict__ gcur, int* __restrict__ binned) {
    __shared__ int bins[B_GRAPHS][BKT_CAP];
    __shared__ int bcnt[B_GRAPHS], sbase[B_GRAPHS], sn[B_GRAPHS];
    int tid = threadIdx.x;
    if (tid < B_GRAPHS) bcnt[tid] = 0;
    __syncthreads();
    int wgbase = blockIdx.x * 2048;
    for (int sub = 0; sub < 2; ++sub) {
        int e0 = wgbase + sub * 1024 + tid * 4;
        int4 s4 = *(const int4*)&src[e0];
        int4 d4 = *(const int4*)&dst[e0];
        int ss[4] = {s4.x, s4.y, s4.z, s4.w};
        int dd[4] = {d4.x, d4.y, d4.z, d4.w};
        #pragma unroll
        for (int k = 0; k < 4; ++k) {
            int b = dd[k] >> 13;
            int pk = ((ss[k] & 8191) << 13) | (dd[k] & 8191);
            int pos = atomicAdd(&bcnt[b], 1);
            if (pos < BKT_CAP) bins[b][pos] = pk;
            else { int gp = atomicAdd(&gcur[b], 1); binned[gp] = pk; }
        }
        __syncthreads();
        if (tid < B_GRAPHS) {
            int nb = min(bcnt[tid], BKT_CAP);
            sn[tid] = nb;
            sbase[tid] = atomicAdd(&gcur[tid], nb);
        }
        __syncthreads();
        int b = tid >> 3, r = tid & 7;
        for (int k = r; k < sn[b]; k += 8) binned[sbase[b] + k] = bins[b][k];
        __syncthreads();
        if (tid < B_GRAPHS) bcnt[tid] = 0;
        __syncthreads();
    }
}

// ---------------------------------------------------------------------------
// Level-A per-graph CSR build (count -> LDS scan -> fill), XCD-local writes.
// ---------------------------------------------------------------------------
__global__ __launch_bounds__(1024)
void csrA_kernel(const int* __restrict__ binned, const int* __restrict__ gbase,
                 const int* __restrict__ gend,
                 int* __restrict__ lo, int* __restrict__ hi, int* __restrict__ csr) {
    __shared__ int cnt[NPG];
    __shared__ int aux[1024];
    int g = blockIdx.x, t = threadIdx.x;
    for (int i = t; i < NPG; i += 1024) cnt[i] = 0;
    __syncthreads();
    int segb = gbase[g], sege = gend[g];
    int nodeb = g * NPG;
    for (int e = segb + t; e < sege; e += 1024)
        atomicAdd(&cnt[binned[e] & 8191], 1);
    __syncthreads();
    int c[8], sum = 0;
    #pragma unroll
    for (int k = 0; k < 8; ++k) { c[k] = cnt[t * 8 + k]; sum += c[k]; }
    aux[t] = sum;
    __syncthreads();
    for (int d = 1; d < 1024; d <<= 1) {
        int v = (t >= d) ? aux[t - d] : 0;
        __syncthreads();
        aux[t] += v;
        __syncthreads();
    }
    int run = segb + aux[t] - sum;
    #pragma unroll
    for (int k = 0; k < 8; ++k) {
        int i = nodeb + t * 8 + k;
        lo[i] = run; hi[i] = run + c[k];
        cnt[t * 8 + k] = run;
        run += c[k];
    }
    __syncthreads();
    for (int e = segb + t; e < sege; e += 1024) {
        int pk = binned[e];
        int p = atomicAdd(&cnt[pk & 8191], 1);
        csr[p] = nodeb + (pk >> 13);
    }
}

// ---------------------------------------------------------------------------
// Level-B per-graph CSR: map edges through c1, drop self-loops (multiset kept).
// Coalesced binned stream; c1 graph-slice (32 KB) is L1-resident.
// ---------------------------------------------------------------------------
__global__ __launch_bounds__(1024)
void csrB_kernel(const int* __restrict__ binned, const int* __restrict__ gbase,
                 const int* __restrict__ gend, const int* __restrict__ c1,
                 int* __restrict__ loB, int* __restrict__ hiB, int* __restrict__ csrB) {
    __shared__ int cnt[1024];
    int g = blockIdx.x, t = threadIdx.x;
    int nodeb = g * NPG, clb = g * 1024;
    cnt[t] = 0;
    __syncthreads();
    int segb = gbase[g], sege = gend[g];
    for (int e = segb + t; e < sege; e += 1024) {
        int pk = binned[e];
        int sc = c1[nodeb + (pk >> 13)];
        int dc = c1[nodeb + (pk & 8191)];
        if (sc != dc) atomicAdd(&cnt[dc - clb], 1);
    }
    __syncthreads();
    int myc = cnt[t];
    for (int d = 1; d < 1024; d <<= 1) {
        int v = (t >= d) ? cnt[t - d] : 0;
        __syncthreads();
        cnt[t] += v;
        __syncthreads();
    }
    int start = segb + cnt[t] - myc;
    loB[clb + t] = start;
    hiB[clb + t] = start + myc;
    __syncthreads();
    cnt[t] = start;
    __syncthreads();
    for (int e = segb + t; e < sege; e += 1024) {
        int pk = binned[e];
        int sc = c1[nodeb + (pk >> 13)];
        int dc = c1[nodeb + (pk & 8191)];
        if (sc != dc) {
            int p = atomicAdd(&cnt[dc - clb], 1);
            csrB[p] = sc;
        }
    }
}

// ---------------------------------------------------------------------------
// Level-C per-graph CSR with LDS bitmap dedupe (256x256 bits = 8 KB):
// one edge pass sets bits; fill emits unique sources straight from the bitmap.
// ---------------------------------------------------------------------------
__global__ __launch_bounds__(1024)
void csrC_kernel(const int* __restrict__ binned, const int* __restrict__ gbase,
                 const int* __restrict__ gend, const int* __restrict__ c12,
                 int* __restrict__ loC, int* __restrict__ hiC, int* __restrict__ csrC) {
    __shared__ unsigned bits[256 * 8];
    __shared__ int scn[256];
    int g = blockIdx.x, t = threadIdx.x;
    int nodeb = g * NPG, clb = g * 256;
    for (int i = t; i < 2048; i += 1024) bits[i] = 0;
    __syncthreads();
    int segb = gbase[g], sege = gend[g];
    for (int e = segb + t; e < sege; e += 1024) {
        int pk = binned[e];
        int sc = c12[nodeb + (pk >> 13)] - clb;
        int dc = c12[nodeb + (pk & 8191)] - clb;
        if (sc != dc) atomicOr(&bits[dc * 8 + (sc >> 5)], 1u << (sc & 31));
    }
    __syncthreads();
    int myc = 0;
    if (t < 256) {
        #pragma unroll
        for (int w = 0; w < 8; ++w) myc += __popc(bits[t * 8 + w]);
        scn[t] = myc;
    }
    __syncthreads();
    for (int d = 1; d < 256; d <<= 1) {
        int v = (t >= d && t < 256) ? scn[t - d] : 0;
        __syncthreads();
        if (t < 256) scn[t] += v;
        __syncthreads();
    }
    if (t < 256) {
        int start = segb + scn[t] - myc;
        loC[clb + t] = start;
        hiC[clb + t] = start + myc;
        int p = start;
        #pragma unroll
        for (int w = 0; w < 8; ++w) {
            unsigned word = bits[t * 8 + w];
            while (word) {
                int b = __ffs(word) - 1;
                word &= word - 1;
                csrC[p++] = clb + w * 32 + b;
            }
        }
    }
}

// ---------------------------------------------------------------------------
// Level-A gather-max conv: wave per dst node; fused pool1 (atomicMax, >=0).
// ---------------------------------------------------------------------------
template<int OUT>
__global__ __launch_bounds__(256)
void gatherw_kernel(const float* __restrict__ a, const float* __restrict__ pos,
                    const float* __restrict__ Wp,
                    const int* __restrict__ lo, const int* __restrict__ hi,
                    const int* __restrict__ csr, const int* __restrict__ cluster,
                    float* __restrict__ out, int n) {
    constexpr int G = 64 / OUT;
    int wave = (blockIdx.x * 256 + threadIdx.x) >> 6;
    int lane = threadIdx.x & 63;
    int ch = lane % OUT, grp = lane / OUT;
    if (wave >= n) return;
    int l = lo[wave], h = hi[wave];
    float m = -1e30f;
    for (int j = l + grp; j < h; j += G)
        m = fmaxf(m, a[(size_t)csr[j] * OUT + ch]);
    #pragma unroll
    for (int st = OUT; st < 64; st <<= 1)
        m = fmaxf(m, __shfl_xor(m, st, 64));
    float px = pos[wave * 3 + 0], py = pos[wave * 3 + 1];
    float cterm = px * Wp[ch] + py * Wp[OUT + ch];
    float val = (h > l) ? fmaxf(m - cterm, 0.0f) : 0.0f;
    if (grp == 0 && val > 0.0f)
        atomicMax((int*)&out[(size_t)cluster[wave] * OUT + ch], __float_as_int(val));
}

// ---------------------------------------------------------------------------
// Coarse gather-max conv: block per node, BLK/OUT streams, LDS max-combine.
// MODE 0: store; MODE 1: atomicMax into out[outmap[v]] (vals >= 0, 0-init).
// ---------------------------------------------------------------------------
template<int OUT, int MODE, int BLK>
__global__ __launch_bounds__(BLK)
void gather4_kernel(const float* __restrict__ a, const float* __restrict__ pos,
                    const float* __restrict__ Wp,
                    const int* __restrict__ lo, const int* __restrict__ hi,
                    const int* __restrict__ csr, const int* __restrict__ outmap,
                    float* __restrict__ out) {
    constexpr int STREAMS = BLK / OUT;
    int v = blockIdx.x;
    int tid = threadIdx.x;
    int ch = tid % OUT, s = tid / OUT;
    int l = lo[v], h = hi[v];
    float m = -1e30f;
    for (int j = l + s; j < h; j += STREAMS)
        m = fmaxf(m, a[(size_t)csr[j] * OUT + ch]);
    __shared__ float sh[BLK];
    sh[tid] = m;
    __syncthreads();
    if (tid < OUT) {
        #pragma unroll
        for (int k = 1; k < STREAMS; ++k) m = fmaxf(m, sh[k * OUT + tid]);
        float px = pos[v * 3 + 0], py = pos[v * 3 + 1];
        float cterm = px * Wp[tid] + py * Wp[OUT + tid];
        float val = (h > l) ? fmaxf(m - cterm, 0.0f) : 0.0f;
        if (MODE == 0) out[(size_t)v * OUT + tid] = val;
        else if (val > 0.0f)
            atomicMax((int*)&out[(size_t)outmap[v] * OUT + tid], __float_as_int(val));
    }
}

// ---------------------------------------------------------------------------
// Voxel cluster id + pos mean accumulation; finalize; out-cells; c12 compose.
// ---------------------------------------------------------------------------
__global__ __launch_bounds__(256)
void cluster_kernel(const float* __restrict__ pos, int* __restrict__ cluster,
                    float* __restrict__ psum, int* __restrict__ cnt,
                    int n, int batch_shift, float inv_grid, int cells) {
    int i = blockIdx.x * 256 + threadIdx.x;
    if (i >= n) return;
    float px = pos[i * 3 + 0], py = pos[i * 3 + 1], pz = pos[i * 3 + 2];
    int ix = min(max((int)floorf(px * inv_grid), 0), cells - 1);
    int iy = min(max((int)floorf(py * inv_grid), 0), cells - 1);
    int c = (i >> batch_shift) * cells * cells + iy * cells + ix;
    cluster[i] = c;
    atomicAdd(&psum[c * 3 + 0], px);
    atomicAdd(&psum[c * 3 + 1], py);
    atomicAdd(&psum[c * 3 + 2], pz);
    atomicAdd(&cnt[c], 1);
}

__global__ __launch_bounds__(256)
void posfin_kernel(const float* __restrict__ pos_sum, const int* __restrict__ cnt,
                   float* __restrict__ pos_new, int n_new) {
    int i = blockIdx.x * 256 + threadIdx.x;
    if (i >= n_new) return;
    float c = fmaxf((float)cnt[i], 1.0f);
    pos_new[i * 3 + 0] = pos_sum[i * 3 + 0] / c;
    pos_new[i * 3 + 1] = pos_sum[i * 3 + 1] / c;
    pos_new[i * 3 + 2] = pos_sum[i * 3 + 2] / c;
}

__global__ __launch_bounds__(256)
void cellout_kernel(const float* __restrict__ pos, int* __restrict__ cell, int n) {
    int i = blockIdx.x * 256 + threadIdx.x;
    if (i >= n) return;
    float px = pos[i * 3 + 0], py = pos[i * 3 + 1];
    int ix = min(max((int)floorf(px * (1.0f / 16.0f)), 0), 7);
    int iy = min(max((int)floorf(py * (1.0f / 16.0f)), 0), 7);
    cell[i] = (i >> 8) * 64 + iy * 8 + ix;
}

__global__ __launch_bounds__(256)
void c12map_kernel(const int* __restrict__ c1, const int* __restrict__ c2,
                   int* __restrict__ c12) {
    int i = blockIdx.x * 256 + threadIdx.x;
    if (i < N_NODES) c12[i] = c2[c1[i]];
}

// ---------------------------------------------------------------------------
// MLP head
// ---------------------------------------------------------------------------
__global__ __launch_bounds__(256)
void mlp1_kernel(const float* __restrict__ g, const float* __restrict__ Wl1,
                 float* __restrict__ hid) {
    int b = blockIdx.x, kc = blockIdx.y, t = threadIdx.x;
    const float* grow = g + (size_t)b * 4096;
    int o0 = t * 4;
    float a0 = 0, a1 = 0, a2 = 0, a3 = 0;
    int k0 = kc * 512;
    for (int k = k0; k < k0 + 512; ++k) {
        float gk = grow[k];
        float4 w = *(const float4*)&Wl1[(size_t)k * 1024 + o0];
        a0 += gk * w.x; a1 += gk * w.y; a2 += gk * w.z; a3 += gk * w.w;
    }
    float* hp = hid + (size_t)b * 1024 + o0;
    atomicAdd(hp + 0, a0);
    atomicAdd(hp + 1, a1);
    atomicAdd(hp + 2, a2);
    atomicAdd(hp + 3, a3);
}

__global__ __launch_bounds__(64)
void mlp2_kernel(const float* __restrict__ hid, const float* __restrict__ bl1,
                 const float* __restrict__ Wl2, const float* __restrict__ bl2,
                 float* __restrict__ out) {
    int b = blockIdx.x, l = threadIdx.x;
    float hv[16];
    #pragma unroll
    for (int i = 0; i < 16; ++i) {
        int idx = l + i * 64;
        hv[i] = fmaxf(hid[(size_t)b * 1024 + idx] + bl1[idx], 0.0f);
    }
    float logits[10];
    #pragma unroll
    for (int c = 0; c < 10; ++c) {
        float p = 0.0f;
        #pragma unroll
        for (int i = 0; i < 16; ++i)
            p += hv[i] * Wl2[(size_t)(l + i * 64) * 10 + c];
        #pragma unroll
        for (int off = 32; off > 0; off >>= 1) p += __shfl_xor(p, off, 64);
        logits[c] = p + bl2[c];
    }
    float m = logits[0];
    #pragma unroll
    for (int c = 1; c < 10; ++c) m = fmaxf(m, logits[c]);
    float ssum = 0.0f;
    #pragma unroll
    for (int c = 0; c < 10; ++c) ssum += expf(logits[c] - m);
    float lse = logf(ssum);
    if (l < 10) out[b * 10 + l] = logits[l] - m - lse;
}

// ---------------------------------------------------------------------------
extern "C" void kernel_launch(void* const* d_in, const int* in_sizes, int n_in,
                              void* d_out, int out_size, void* d_ws, size_t ws_size,
                              hipStream_t stream) {
    const float* x    = (const float*)d_in[0];
    const float* pos0 = (const float*)d_in[1];
    const int*   ei   = (const int*)d_in[2];
    const float* W1 = (const float*)d_in[4];  const float* b1 = (const float*)d_in[5];
    const float* W2 = (const float*)d_in[6];  const float* b2 = (const float*)d_in[7];
    const float* W3 = (const float*)d_in[8];  const float* b3 = (const float*)d_in[9];
    const float* W4 = (const float*)d_in[10]; const float* b4 = (const float*)d_in[11];
    const float* W5 = (const float*)d_in[12]; const float* b5 = (const float*)d_in[13];
    const float* Wl1 = (const float*)d_in[14]; const float* bl1 = (const float*)d_in[15];
    const float* Wl2 = (const float*)d_in[16]; const float* bl2 = (const float*)d_in[17];
    const int* src0 = ei;
    const int* dst0 = ei + NE;
    float* out = (float*)d_out;

    float* w = (float*)d_ws;
    size_t off = 0;
    auto alloc = [&](size_t n) { float* p = w + off; off += n; return p; };

    // --- zero-init region (one memset) ---
    int*   gcnt   = (int*)alloc(32);
    float* hp1    = alloc((size_t)N1 * 16);
    float* psum1  = alloc((size_t)N1 * 3);
    int*   icnt1  = (int*)alloc(N1);
    float* hp2    = alloc((size_t)N2 * 32);
    float* psum2  = alloc((size_t)N2 * 3);
    int*   icnt2  = (int*)alloc(N2);
    float* g      = alloc((size_t)B_GRAPHS * 4096);
    float* hid    = alloc((size_t)B_GRAPHS * 1024);
    size_t zero_bytes = off * sizeof(float);
    // --- abuf (a at every level) ---
    float* abuf = alloc((size_t)N_NODES * 16);
    // --- union: binned (alive through csrC) then h2/h4 ---
    float* ubase = alloc((size_t)NE);                       // 2.1M floats
    int*   binned = (int*)ubase;                            // packed (s<<13|d), per-graph
    float* h2   = ubase;                                    // N1*32 = 1M (after csrC)
    float* h4   = h2 + (size_t)N1 * 32;                     // N2*64 = 0.5M
    // --- CSR buffers ---
    int* csr0 = (int*)alloc(NE);      // level A; reused as level-C csr after gatherw
    int* csr1 = (int*)alloc(NE);      // level B
    int* loA  = (int*)alloc(N_NODES);
    int* hiA  = (int*)alloc(N_NODES);
    int* loB  = (int*)alloc(N1);
    int* hiB  = (int*)alloc(N1);
    int* loC  = (int*)alloc(N2);
    int* hiC  = (int*)alloc(N2);
    // --- misc ---
    float* pos1 = alloc((size_t)N1 * 3);
    float* pos2 = alloc((size_t)N2 * 3);
    int* cell = (int*)alloc(N2);
    int* c1   = (int*)alloc(N_NODES);
    int* c2   = (int*)alloc(N1);
    int* c12  = (int*)alloc(N_NODES);
    int* gbase = (int*)alloc(64);
    int* gcur  = (int*)alloc(64);
    (void)ws_size; (void)in_sizes; (void)n_in; (void)out_size;

    hipMemsetAsync(d_ws, 0, zero_bytes, stream);

    // ===== level A: CSR build + conv1 (fused pool1) =====
    node_a_kernel<1, 16><<<N_NODES / 256, 256, 0, stream>>>(x, pos0, W1, b1, abuf, N_NODES);
    precount_kernel<<<256, 256, 0, stream>>>(dst0, gcnt);
    gscan_kernel<<<1, 64, 0, stream>>>(gcnt, gbase, gcur);
    bucket_kernel<<<NE / 2048, 256, 0, stream>>>(src0, dst0, gcur, binned);
    csrA_kernel<<<B_GRAPHS, 1024, 0, stream>>>(binned, gbase, gcur, loA, hiA, csr0);
    cluster_kernel<<<N_NODES / 256, 256, 0, stream>>>(pos0, c1, psum1, icnt1, N_NODES, 13, 0.25f, 32);
    gatherw_kernel<16><<<N_NODES / 4, 256, 0, stream>>>(abuf, pos0, W1 + 16,
                                                        loA, hiA, csr0, c1, hp1, N_NODES);
    posfin_kernel<<<N1 / 256, 256, 0, stream>>>(psum1, icnt1, pos1, N1);

    // ===== cluster maps + coarse CSRs (from graph-major binned stream) =====
    cluster_kernel<<<N1 / 256, 256, 0, stream>>>(pos1, c2, psum2, icnt2, N1, 10, 0.125f, 16);
    posfin_kernel<<<N2 / 256, 256, 0, stream>>>(psum2, icnt2, pos2, N2);
    c12map_kernel<<<N_NODES / 256, 256, 0, stream>>>(c1, c2, c12);
    csrB_kernel<<<B_GRAPHS, 1024, 0, stream>>>(binned, gbase, gcur, c1, loB, hiB, csr1);
    csrC_kernel<<<B_GRAPHS, 1024, 0, stream>>>(binned, gbase, gcur, c12, loC, hiC, csr0);

    // ===== level B: conv2 (store), conv3 (fused pool2) =====
    node_a_kernel<16, 32><<<N1 / 256, 256, 0, stream>>>(hp1, pos1, W2, b2, abuf, N1);
    gather4_kernel<32, 0, 512><<<N1, 512, 0, stream>>>(abuf, pos1, W2 + 512,
                                                       loB, hiB, csr1, nullptr, h2);
    node_a_kernel<32, 32><<<N1 / 256, 256, 0, stream>>>(h2, pos1, W3, b3, abuf, N1);
    gather4_kernel<32, 1, 512><<<N1, 512, 0, stream>>>(abuf, pos1, W3 + 1024,
                                                       loB, hiB, csr1, c2, hp2);

    // ===== level C: conv4 (store), conv5 (fused pool_out) =====
    node_a_kernel<32, 64><<<N2 / 256, 256, 0, stream>>>(hp2, pos2, W4, b4, abuf, N2);
    gather4_kernel<64, 0, 512><<<N2, 512, 0, stream>>>(abuf, pos2, W4 + 2048,
                                                       loC, hiC, csr0, nullptr, h4);
    node_a_kernel<64, 64><<<N2 / 256, 256, 0, stream>>>(h4, pos2, W5, b5, abuf, N2);
    cellout_kernel<<<N2 / 256, 256, 0, stream>>>(pos2, cell, N2);
    gather4_kernel<64, 1, 512><<<N2, 512, 0, stream>>>(abuf, pos2, W5 + 4096,
                                                       loC, hiC, csr0, cell, g);

    // ===== MLP head =====
    mlp1_kernel<<<dim3(32, 8), 256, 0, stream>>>(g, Wl1, hid);
    mlp2_kernel<<<32, 64, 0, stream>>>(hid, bl1, Wl2, bl2, out);
}

// Round 7
// 666.093 us; speedup vs baseline: 1.7711x; 1.2970x over previous
//
#include <hip/hip_runtime.h>
#include <cstdint>
#include <cstddef>

#define B_GRAPHS 32
#define NPG      8192
#define N_NODES  (B_GRAPHS * NPG)   // 262144
#define DEG      8
#define NE       (N_NODES * DEG)    // 2097152
#define N1       32768              // B * 32*32  (grid 4)
#define N2       8192               // B * 16*16  (grid 8)
#define BKT_CAP  80
#define CPG      8                  // chunks per graph for parallel sorts

// ---------------------------------------------------------------------------
// Node-level precompute: a[i,o] = b[o] + sum_k h[i,k]*W[k,o] + px*W[IN,o] + py*W[IN+1,o]
// ---------------------------------------------------------------------------
template<int IN, int OUT>
__global__ __launch_bounds__(256)
void node_a_kernel(const float* __restrict__ h, const float* __restrict__ pos,
                   const float* __restrict__ W, const float* __restrict__ bias,
                   float* __restrict__ a, int n) {
    constexpr int FEAT = IN + 2;
    __shared__ float Ws[FEAT * OUT + OUT];
    for (int i = threadIdx.x; i < FEAT * OUT; i += 256) Ws[i] = W[i];
    for (int i = threadIdx.x; i < OUT; i += 256) Ws[FEAT * OUT + i] = bias[i];
    __syncthreads();
    int i = blockIdx.x * 256 + threadIdx.x;
    if (i >= n) return;

    float acc[OUT];
    #pragma unroll
    for (int o = 0; o < OUT; ++o) acc[o] = Ws[FEAT * OUT + o];

    float px = pos[i * 3 + 0], py = pos[i * 3 + 1];
    #pragma unroll
    for (int o = 0; o < OUT; ++o)
        acc[o] += px * Ws[IN * OUT + o] + py * Ws[(IN + 1) * OUT + o];

    if constexpr (IN % 4 == 0) {
        const float4* h4 = (const float4*)(h + (size_t)i * IN);
        for (int k4 = 0; k4 < IN / 4; ++k4) {
            float4 f = h4[k4];
            #pragma unroll
            for (int o = 0; o < OUT; ++o) {
                acc[o] += f.x * Ws[(k4 * 4 + 0) * OUT + o];
                acc[o] += f.y * Ws[(k4 * 4 + 1) * OUT + o];
                acc[o] += f.z * Ws[(k4 * 4 + 2) * OUT + o];
                acc[o] += f.w * Ws[(k4 * 4 + 3) * OUT + o];
            }
        }
    } else {
        for (int k = 0; k < IN; ++k) {
            float f = h[(size_t)i * IN + k];
            #pragma unroll
            for (int o = 0; o < OUT; ++o) acc[o] += f * Ws[k * OUT + o];
        }
    }
    float* ap = a + (size_t)i * OUT;
    #pragma unroll
    for (int o = 0; o < OUT; ++o) ap[o] = acc[o];
}

// ---------------------------------------------------------------------------
// Per-graph edge histogram (gcnt zeroed) + tiny serial scan.
// ---------------------------------------------------------------------------
__global__ __launch_bounds__(256)
void precount_kernel(const int* __restrict__ dst, int* __restrict__ gcnt) {
    __shared__ int hist[B_GRAPHS];
    if (threadIdx.x < B_GRAPHS) hist[threadIdx.x] = 0;
    __syncthreads();
    int gid = blockIdx.x * 256 + threadIdx.x;
    for (int e = gid; e < NE; e += 256 * 256)
        atomicAdd(&hist[dst[e] >> 13], 1);
    __syncthreads();
    if (threadIdx.x < B_GRAPHS) atomicAdd(&gcnt[threadIdx.x], hist[threadIdx.x]);
}

__global__ void gscan_kernel(const int* __restrict__ gcnt, int* __restrict__ gbase,
                             int* __restrict__ gcur) {
    if (threadIdx.x == 0) {
        int run = 0;
        for (int g = 0; g < B_GRAPHS; ++g) {
            gbase[g] = run; gcur[g] = run;
            run += gcnt[g];
        }
        gbase[B_GRAPHS] = run;
    }
}

// ---------------------------------------------------------------------------
// Bucket edges by graph, packed local (src<<13 | dst). Coalesced flushes.
// ---------------------------------------------------------------------------
__global__ __launch_bounds__(256)
void bucket_kernel(const int* __restrict__ src, const int* __restrict__ dst,
                   int* __restrict__ gcur, int* __restrict__ binned) {
    __shared__ int bins[B_GRAPHS][BKT_CAP];
    __shared__ int bcnt[B_GRAPHS], sbase[B_GRAPHS], sn[B_GRAPHS];
    int tid = threadIdx.x;
    if (tid < B_GRAPHS) bcnt[tid] = 0;
    __syncthreads();
    int wgbase = blockIdx.x * 2048;
    for (int sub = 0; sub < 2; ++sub) {
        int e0 = wgbase + sub * 1024 + tid * 4;
        int4 s4 = *(const int4*)&src[e0];
        int4 d4 = *(const int4*)&dst[e0];
        int ss[4] = {s4.x, s4.y, s4.z, s4.w};
        int dd[4] = {d4.x, d4.y, d4.z, d4.w};
        #pragma unroll
        for (int k = 0; k < 4; ++k) {
            int b = dd[k] >> 13;
            int pk = ((ss[k] & 8191) << 13) | (dd[k] & 8191);
            int pos = atomicAdd(&bcnt[b], 1);
            if (pos < BKT_CAP) bins[b][pos] = pk;
            else { int gp = atomicAdd(&gcur[b], 1); binned[gp] = pk; }
        }
        __syncthreads();
        if (tid < B_GRAPHS) {
            int nb = min(bcnt[tid], BKT_CAP);
            sn[tid] = nb;
            sbase[tid] = atomicAdd(&gcur[tid], nb);
        }
        __syncthreads();
        int b = tid >> 3, r = tid & 7;
        for (int k = r; k < sn[b]; k += 8) binned[sbase[b] + k] = bins[b][k];
        __syncthreads();
        if (tid < B_GRAPHS) bcnt[tid] = 0;
        __syncthreads();
    }
}

// ---------------------------------------------------------------------------
// Parallel chunked counting sort (hist -> global scan -> fill), 8 chunks/graph.
// LEVB 0: bin = dst_local>>4 (512 bins), keep all, value = packed edge.
// LEVB 1: bin = c1[dst] local (1024 bins), drop self-loops, value = c1[src] global.
// H/S layout: [g][bin][chunk], so a single global exclusive scan of H yields
// every (g,bin,chunk) output cursor AND per-bin lo/hi (= S at chunk 0).
// ---------------------------------------------------------------------------
template<int BINS, int LEVB>
__global__ __launch_bounds__(1024)
void sort_hist_kernel(const int* __restrict__ binned, const int* __restrict__ gbase,
                      const int* __restrict__ gend, const int* __restrict__ c1,
                      int* __restrict__ H) {
    __shared__ int hist[BINS];
    int wg = blockIdx.x, g = wg >> 3, sub = wg & 7, t = threadIdx.x;
    for (int i = t; i < BINS; i += 1024) hist[i] = 0;
    __syncthreads();
    int segb = gbase[g], sege = gend[g];
    int csz = (sege - segb + CPG - 1) / CPG;
    int e0 = segb + sub * csz, e1 = min(e0 + csz, sege);
    int nodeb = g * NPG;
    for (int e = e0 + t; e < e1; e += 1024) {
        int pk = binned[e];
        if (LEVB) {
            int sc = c1[nodeb + (pk >> 13)];
            int dc = c1[nodeb + (pk & 8191)];
            if (sc != dc) atomicAdd(&hist[dc & (BINS - 1)], 1);
        } else {
            atomicAdd(&hist[(pk & 8191) >> 4], 1);
        }
    }
    __syncthreads();
    for (int b = t; b < BINS; b += 1024)
        H[(size_t)(g * BINS + b) * CPG + sub] = hist[b];
}

template<int BINS, int LEVB>
__global__ __launch_bounds__(1024)
void sort_fill_kernel(const int* __restrict__ binned, const int* __restrict__ gbase,
                      const int* __restrict__ gend, const int* __restrict__ c1,
                      const int* __restrict__ S, int* __restrict__ outv) {
    __shared__ int cur[BINS];
    int wg = blockIdx.x, g = wg >> 3, sub = wg & 7, t = threadIdx.x;
    for (int b = t; b < BINS; b += 1024)
        cur[b] = S[(size_t)(g * BINS + b) * CPG + sub];
    __syncthreads();
    int segb = gbase[g], sege = gend[g];
    int csz = (sege - segb + CPG - 1) / CPG;
    int e0 = segb + sub * csz, e1 = min(e0 + csz, sege);
    int nodeb = g * NPG;
    for (int e = e0 + t; e < e1; e += 1024) {
        int pk = binned[e];
        if (LEVB) {
            int sc = c1[nodeb + (pk >> 13)];
            int dc = c1[nodeb + (pk & 8191)];
            if (sc != dc) {
                int p = atomicAdd(&cur[dc & (BINS - 1)], 1);
                outv[p] = sc;                       // global coarse id
            }
        } else {
            int p = atomicAdd(&cur[(pk & 8191) >> 4], 1);
            outv[p] = pk;
        }
    }
}

// ---------------------------------------------------------------------------
// Hierarchical exclusive scan (n % 1024 == 0, n/1024 <= 256). cursor optional.
// ---------------------------------------------------------------------------
__global__ __launch_bounds__(256)
void scan_reduce_kernel(const int* __restrict__ counts, int* __restrict__ blocksums) {
    int t = threadIdx.x;
    int4 v = *(const int4*)&counts[blockIdx.x * 1024 + t * 4];
    int s = v.x + v.y + v.z + v.w;
    #pragma unroll
    for (int off = 32; off > 0; off >>= 1) s += __shfl_xor(s, off, 64);
    __shared__ int ws[4];
    if ((t & 63) == 0) ws[t >> 6] = s;
    __syncthreads();
    if (t == 0) blocksums[blockIdx.x] = ws[0] + ws[1] + ws[2] + ws[3];
}

__global__ __launch_bounds__(256)
void scan_blocks_kernel(const int* __restrict__ blocksums, int* __restrict__ blockpref,
                        int* __restrict__ offsets, int nb, int n) {
    __shared__ int sh[256];
    int t = threadIdx.x;
    int v = (t < nb) ? blocksums[t] : 0;
    sh[t] = v;
    __syncthreads();
    #pragma unroll
    for (int d = 1; d < 256; d <<= 1) {
        int u = (t >= d) ? sh[t - d] : 0;
        __syncthreads();
        sh[t] += u;
        __syncthreads();
    }
    if (t < nb) blockpref[t] = sh[t] - v;
    if (t == 255) offsets[n] = sh[255];
}

__global__ __launch_bounds__(256)
void scan_write_kernel(const int* __restrict__ counts, const int* __restrict__ blockpref,
                       int* __restrict__ offsets, int* __restrict__ cursor) {
    int b = blockIdx.x, t = threadIdx.x;
    int base = b * 1024 + t * 4;
    int4 v = *(const int4*)&counts[base];
    int s = v.x + v.y + v.z + v.w;
    __shared__ int sh[256];
    sh[t] = s;
    __syncthreads();
    #pragma unroll
    for (int d = 1; d < 256; d <<= 1) {
        int u = (t >= d) ? sh[t - d] : 0;
        __syncthreads();
        sh[t] += u;
        __syncthreads();
    }
    int pref = blockpref[b] + sh[t] - s;
    int4 o;
    o.x = pref;
    o.y = pref + v.x;
    o.z = o.y + v.y;
    o.w = o.z + v.z;
    *(int4*)&offsets[base] = o;
    if (cursor) *(int4*)&cursor[base] = o;
}

// ---------------------------------------------------------------------------
// Level-A fused conv1+pool1: one wg per 16-dst bucket; per-(dst,ch) LDS
// atomicMax slots with order-preserving uint keys (a can be negative).
// ---------------------------------------------------------------------------
__global__ __launch_bounds__(256)
void gatherA_kernel(const float* __restrict__ a, const float* __restrict__ pos,
                    const float* __restrict__ Wp, const int* __restrict__ S,
                    const int* __restrict__ sortedA, const int* __restrict__ c1,
                    float* __restrict__ hp1) {
    __shared__ unsigned slot[256];
    int v = blockIdx.x;                  // g*512 + bucket
    int g = v >> 9;
    int t = threadIdx.x;
    slot[t] = 0u;                        // < okey of any real float
    __syncthreads();
    int start = S[(size_t)v * CPG], end = S[(size_t)(v + 1) * CPG];
    int nodeb = g * NPG;
    int ch = t & 15, el = t >> 4;
    for (int j = start + el; j < end; j += 16) {
        int pk = sortedA[j];
        float val = a[(size_t)(nodeb + (pk >> 13)) * 16 + ch];
        unsigned u = __float_as_uint(val);
        unsigned key = (u & 0x80000000u) ? ~u : (u | 0x80000000u);
        atomicMax(&slot[((pk & 15) << 4) + ch], key);
    }
    __syncthreads();
    int dl = t >> 4;
    unsigned k = slot[(dl << 4) + ch];
    if (k) {
        unsigned u = (k & 0x80000000u) ? (k ^ 0x80000000u) : ~k;
        float m = __uint_as_float(u);
        int dst = nodeb + ((v & 511) << 4) + dl;
        float px = pos[dst * 3 + 0], py = pos[dst * 3 + 1];
        float val = fmaxf(m - (px * Wp[ch] + py * Wp[16 + ch]), 0.0f);
        if (val > 0.0f)
            atomicMax((int*)&hp1[(size_t)c1[dst] * 16 + ch], __float_as_int(val));
    }
}

// ---------------------------------------------------------------------------
// Level-C dedupe bitmap (parallel): LDS bitmap per chunk, merge via atomicOr.
// ---------------------------------------------------------------------------
__global__ __launch_bounds__(1024)
void bitC_kernel(const int* __restrict__ binned, const int* __restrict__ gbase,
                 const int* __restrict__ gend, const int* __restrict__ c12,
                 unsigned* __restrict__ bitsG) {
    __shared__ unsigned bits[2048];
    int wg = blockIdx.x, g = wg >> 3, sub = wg & 7, t = threadIdx.x;
    for (int i = t; i < 2048; i += 1024) bits[i] = 0;
    __syncthreads();
    int segb = gbase[g], sege = gend[g];
    int csz = (sege - segb + CPG - 1) / CPG;
    int e0 = segb + sub * csz, e1 = min(e0 + csz, sege);
    int nodeb = g * NPG, clb = g * 256;
    for (int e = e0 + t; e < e1; e += 1024) {
        int pk = binned[e];
        int sc = c12[nodeb + (pk >> 13)] - clb;
        int dc = c12[nodeb + (pk & 8191)] - clb;
        if (sc != dc) atomicOr(&bits[(dc << 3) + (sc >> 5)], 1u << (sc & 31));
    }
    __syncthreads();
    for (int i = t; i < 2048; i += 1024) {
        unsigned wv = bits[i];
        if (wv) atomicOr(&bitsG[((size_t)g << 11) + i], wv);
    }
}

__global__ __launch_bounds__(256)
void popcC_kernel(const unsigned* __restrict__ bitsG, int* __restrict__ pc) {
    int i = blockIdx.x * 256 + threadIdx.x;      // 8192
    int s = 0;
    #pragma unroll
    for (int k = 0; k < 8; ++k) s += __popc(bitsG[((size_t)i << 3) + k]);
    pc[i] = s;
}

__global__ __launch_bounds__(256)
void emitC_kernel(const unsigned* __restrict__ bitsG, const int* __restrict__ SC,
                  int* __restrict__ csrC) {
    int i = blockIdx.x * 256 + threadIdx.x;      // dst global C id
    int clb = (i >> 8) << 8;
    int p = SC[i];
    #pragma unroll
    for (int w = 0; w < 8; ++w) {
        unsigned word = bitsG[((size_t)i << 3) + w];
        while (word) {
            int b = __ffs(word) - 1;
            word &= word - 1;
            csrC[p++] = clb + (w << 5) + b;
        }
    }
}

// ---------------------------------------------------------------------------
// Coarse gather-max conv: block per node, BLK/OUT streams, LDS max-combine.
// lo/hi read from S with stride (S layout [v][chunk] or plain).
// MODE 0: store; MODE 1: atomicMax into out[outmap[v]] (vals >= 0, 0-init).
// ---------------------------------------------------------------------------
template<int OUT, int MODE, int BLK, int STRIDE>
__global__ __launch_bounds__(BLK)
void gather4_kernel(const float* __restrict__ a, const float* __restrict__ pos,
                    const float* __restrict__ Wp, const int* __restrict__ S,
                    const int* __restrict__ csr, const int* __restrict__ outmap,
                    float* __restrict__ out) {
    constexpr int STREAMS = BLK / OUT;
    int v = blockIdx.x;
    int tid = threadIdx.x;
    int ch = tid % OUT, s = tid / OUT;
    int l = S[(size_t)v * STRIDE], h = S[(size_t)(v + 1) * STRIDE];
    float m = -1e30f;
    for (int j = l + s; j < h; j += STREAMS)
        m = fmaxf(m, a[(size_t)csr[j] * OUT + ch]);
    __shared__ float sh[BLK];
    sh[tid] = m;
    __syncthreads();
    if (tid < OUT) {
        #pragma unroll
        for (int k = 1; k < STREAMS; ++k) m = fmaxf(m, sh[k * OUT + tid]);
        float px = pos[v * 3 + 0], py = pos[v * 3 + 1];
        float cterm = px * Wp[tid] + py * Wp[OUT + tid];
        float val = (h > l) ? fmaxf(m - cterm, 0.0f) : 0.0f;
        if (MODE == 0) out[(size_t)v * OUT + tid] = val;
        else if (val > 0.0f)
            atomicMax((int*)&out[(size_t)outmap[v] * OUT + tid], __float_as_int(val));
    }
}

// ---------------------------------------------------------------------------
// Voxel cluster id + pos mean accumulation; finalize; out-cells; c12 compose.
// ---------------------------------------------------------------------------
__global__ __launch_bounds__(256)
void cluster_kernel(const float* __restrict__ pos, int* __restrict__ cluster,
                    float* __restrict__ psum, int* __restrict__ cnt,
                    int n, int batch_shift, float inv_grid, int cells) {
    int i = blockIdx.x * 256 + threadIdx.x;
    if (i >= n) return;
    float px = pos[i * 3 + 0], py = pos[i * 3 + 1], pz = pos[i * 3 + 2];
    int ix = min(max((int)floorf(px * inv_grid), 0), cells - 1);
    int iy = min(max((int)floorf(py * inv_grid), 0), cells - 1);
    int c = (i >> batch_shift) * cells * cells + iy * cells + ix;
    cluster[i] = c;
    atomicAdd(&psum[c * 3 + 0], px);
    atomicAdd(&psum[c * 3 + 1], py);
    atomicAdd(&psum[c * 3 + 2], pz);
    atomicAdd(&cnt[c], 1);
}

__global__ __launch_bounds__(256)
void posfin_kernel(const float* __restrict__ pos_sum, const int* __restrict__ cnt,
                   float* __restrict__ pos_new, int n_new) {
    int i = blockIdx.x * 256 + threadIdx.x;
    if (i >= n_new) return;
    float c = fmaxf((float)cnt[i], 1.0f);
    pos_new[i * 3 + 0] = pos_sum[i * 3 + 0] / c;
    pos_new[i * 3 + 1] = pos_sum[i * 3 + 1] / c;
    pos_new[i * 3 + 2] = pos_sum[i * 3 + 2] / c;
}

__global__ __launch_bounds__(256)
void cellout_kernel(const float* __restrict__ pos, int* __restrict__ cell, int n) {
    int i = blockIdx.x * 256 + threadIdx.x;
    if (i >= n) return;
    float px = pos[i * 3 + 0], py = pos[i * 3 + 1];
    int ix = min(max((int)floorf(px * (1.0f / 16.0f)), 0), 7);
    int iy = min(max((int)floorf(py * (1.0f / 16.0f)), 0), 7);
    cell[i] = (i >> 8) * 64 + iy * 8 + ix;
}

__global__ __launch_bounds__(256)
void c12map_kernel(const int* __restrict__ c1, const int* __restrict__ c2,
                   int* __restrict__ c12) {
    int i = blockIdx.x * 256 + threadIdx.x;
    if (i < N_NODES) c12[i] = c2[c1[i]];
}

// ---------------------------------------------------------------------------
// MLP head
// ---------------------------------------------------------------------------
__global__ __launch_bounds__(256)
void mlp1_kernel(const float* __restrict__ g, const float* __restrict__ Wl1,
                 float* __restrict__ hid) {
    int b = blockIdx.x, kc = blockIdx.y, t = threadIdx.x;
    const float* grow = g + (size_t)b * 4096;
    int o0 = t * 4;
    float a0 = 0, a1 = 0, a2 = 0, a3 = 0;
    int k0 = kc * 512;
    for (int k = k0; k < k0 + 512; ++k) {
        float gk = grow[k];
        float4 w = *(const float4*)&Wl1[(size_t)k * 1024 + o0];
        a0 += gk * w.x; a1 += gk * w.y; a2 += gk * w.z; a3 += gk * w.w;
    }
    float* hp = hid + (size_t)b * 1024 + o0;
    atomicAdd(hp + 0, a0);
    atomicAdd(hp + 1, a1);
    atomicAdd(hp + 2, a2);
    atomicAdd(hp + 3, a3);
}

__global__ __launch_bounds__(64)
void mlp2_kernel(const float* __restrict__ hid, const float* __restrict__ bl1,
                 const float* __restrict__ Wl2, const float* __restrict__ bl2,
                 float* __restrict__ out) {
    int b = blockIdx.x, l = threadIdx.x;
    float hv[16];
    #pragma unroll
    for (int i = 0; i < 16; ++i) {
        int idx = l + i * 64;
        hv[i] = fmaxf(hid[(size_t)b * 1024 + idx] + bl1[idx], 0.0f);
    }
    float logits[10];
    #pragma unroll
    for (int c = 0; c < 10; ++c) {
        float p = 0.0f;
        #pragma unroll
        for (int i = 0; i < 16; ++i)
            p += hv[i] * Wl2[(size_t)(l + i * 64) * 10 + c];
        #pragma unroll
        for (int off = 32; off > 0; off >>= 1) p += __shfl_xor(p, off, 64);
        logits[c] = p + bl2[c];
    }
    float m = logits[0];
    #pragma unroll
    for (int c = 1; c < 10; ++c) m = fmaxf(m, logits[c]);
    float ssum = 0.0f;
    #pragma unroll
    for (int c = 0; c < 10; ++c) ssum += expf(logits[c] - m);
    float lse = logf(ssum);
    if (l < 10) out[b * 10 + l] = logits[l] - m - lse;
}

// ---------------------------------------------------------------------------
extern "C" void kernel_launch(void* const* d_in, const int* in_sizes, int n_in,
                              void* d_out, int out_size, void* d_ws, size_t ws_size,
                              hipStream_t stream) {
    const float* x    = (const float*)d_in[0];
    const float* pos0 = (const float*)d_in[1];
    const int*   ei   = (const int*)d_in[2];
    const float* W1 = (const float*)d_in[4];  const float* b1 = (const float*)d_in[5];
    const float* W2 = (const float*)d_in[6];  const float* b2 = (const float*)d_in[7];
    const float* W3 = (const float*)d_in[8];  const float* b3 = (const float*)d_in[9];
    const float* W4 = (const float*)d_in[10]; const float* b4 = (const float*)d_in[11];
    const float* W5 = (const float*)d_in[12]; const float* b5 = (const float*)d_in[13];
    const float* Wl1 = (const float*)d_in[14]; const float* bl1 = (const float*)d_in[15];
    const float* Wl2 = (const float*)d_in[16]; const float* bl2 = (const float*)d_in[17];
    const int* src0 = ei;
    const int* dst0 = ei + NE;
    float* out = (float*)d_out;

    float* w = (float*)d_ws;
    size_t off = 0;
    auto alloc = [&](size_t n) { float* p = w + off; off += (n + 3) & ~(size_t)3; return p; };

    // --- zero-init region (one memset) ---
    int*      gcnt  = (int*)alloc(32);
    unsigned* bitsG = (unsigned*)alloc(B_GRAPHS * 2048);   // level-C bitmap
    float* hp1   = alloc((size_t)N1 * 16);
    float* psum1 = alloc((size_t)N1 * 3);
    int*   icnt1 = (int*)alloc(N1);
    float* hp2   = alloc((size_t)N2 * 32);
    float* psum2 = alloc((size_t)N2 * 3);
    int*   icnt2 = (int*)alloc(N2);
    float* g     = alloc((size_t)B_GRAPHS * 4096);
    float* hid   = alloc((size_t)B_GRAPHS * 1024);
    size_t zero_bytes = off * sizeof(float);
    // --- abuf (a at every level) ---
    float* abuf = alloc((size_t)N_NODES * 16);
    // --- union 1: binned (dead after bitC) -> h2, h4 ---
    float* ubase = alloc((size_t)NE);
    int*   binned = (int*)ubase;
    float* h2 = ubase;                        // N1*32 = 1M
    float* h4 = h2 + (size_t)N1 * 32;         // N2*64 = 0.5M
    // --- union 2: sortedA (dead after gatherA) -> csrC ---
    int* sortedA = (int*)alloc(NE);
    int* csrC = sortedA;
    // --- rest ---
    int* csrB = (int*)alloc(NE);
    int* H   = (int*)alloc((size_t)B_GRAPHS * 1024 * CPG + 4);   // max of A/B hist
    int* S_A = (int*)alloc((size_t)B_GRAPHS * 512 * CPG + 4);
    int* S_B = (int*)alloc((size_t)B_GRAPHS * 1024 * CPG + 4);
    int* pc  = (int*)alloc(N2);
    int* SC  = (int*)alloc(N2 + 4);
    float* pos1 = alloc((size_t)N1 * 3);
    float* pos2 = alloc((size_t)N2 * 3);
    int* cell = (int*)alloc(N2);
    int* c1   = (int*)alloc(N_NODES);
    int* c2   = (int*)alloc(N1);
    int* c12  = (int*)alloc(N_NODES);
    int* gbase = (int*)alloc(64);
    int* gcur  = (int*)alloc(64);
    int* blocksums = (int*)alloc(512);
    int* blockpref = (int*)alloc(512);
    (void)ws_size; (void)in_sizes; (void)n_in; (void)out_size;

    hipMemsetAsync(d_ws, 0, zero_bytes, stream);

    auto hscan = [&](const int* cnts, int* offs, int n) {
        scan_reduce_kernel<<<n / 1024, 256, 0, stream>>>(cnts, blocksums);
        scan_blocks_kernel<<<1, 256, 0, stream>>>(blocksums, blockpref, offs, n / 1024, n);
        scan_write_kernel<<<n / 1024, 256, 0, stream>>>(cnts, blockpref, offs, nullptr);
    };

    // ===== level A: bucket by graph, bucket-16 sort, fused conv1+pool1 =====
    node_a_kernel<1, 16><<<N_NODES / 256, 256, 0, stream>>>(x, pos0, W1, b1, abuf, N_NODES);
    precount_kernel<<<256, 256, 0, stream>>>(dst0, gcnt);
    gscan_kernel<<<1, 64, 0, stream>>>(gcnt, gbase, gcur);
    bucket_kernel<<<NE / 2048, 256, 0, stream>>>(src0, dst0, gcur, binned);
    sort_hist_kernel<512, 0><<<B_GRAPHS * CPG, 1024, 0, stream>>>(binned, gbase, gcur, nullptr, H);
    hscan(H, S_A, B_GRAPHS * 512 * CPG);
    sort_fill_kernel<512, 0><<<B_GRAPHS * CPG, 1024, 0, stream>>>(binned, gbase, gcur, nullptr, S_A, sortedA);
    cluster_kernel<<<N_NODES / 256, 256, 0, stream>>>(pos0, c1, psum1, icnt1, N_NODES, 13, 0.25f, 32);
    gatherA_kernel<<<B_GRAPHS * 512, 256, 0, stream>>>(abuf, pos0, W1 + 16, S_A, sortedA, c1, hp1);
    posfin_kernel<<<N1 / 256, 256, 0, stream>>>(psum1, icnt1, pos1, N1);

    // ===== cluster maps =====
    cluster_kernel<<<N1 / 256, 256, 0, stream>>>(pos1, c2, psum2, icnt2, N1, 10, 0.125f, 16);
    posfin_kernel<<<N2 / 256, 256, 0, stream>>>(psum2, icnt2, pos2, N2);
    c12map_kernel<<<N_NODES / 256, 256, 0, stream>>>(c1, c2, c12);

    // ===== level-B CSR (1024-bin counting sort) =====
    sort_hist_kernel<1024, 1><<<B_GRAPHS * CPG, 1024, 0, stream>>>(binned, gbase, gcur, c1, H);
    hscan(H, S_B, B_GRAPHS * 1024 * CPG);
    sort_fill_kernel<1024, 1><<<B_GRAPHS * CPG, 1024, 0, stream>>>(binned, gbase, gcur, c1, S_B, csrB);

    // ===== level-C CSR (parallel bitmap dedupe) =====
    bitC_kernel<<<B_GRAPHS * CPG, 1024, 0, stream>>>(binned, gbase, gcur, c12, bitsG);
    popcC_kernel<<<N2 / 256, 256, 0, stream>>>(bitsG, pc);
    hscan(pc, SC, N2);
    emitC_kernel<<<N2 / 256, 256, 0, stream>>>(bitsG, SC, csrC);

    // ===== level B: conv2 (store), conv3 (fused pool2) =====
    node_a_kernel<16, 32><<<N1 / 256, 256, 0, stream>>>(hp1, pos1, W2, b2, abuf, N1);
    gather4_kernel<32, 0, 512, CPG><<<N1, 512, 0, stream>>>(abuf, pos1, W2 + 512, S_B, csrB, nullptr, h2);
    node_a_kernel<32, 32><<<N1 / 256, 256, 0, stream>>>(h2, pos1, W3, b3, abuf, N1);
    gather4_kernel<32, 1, 512, CPG><<<N1, 512, 0, stream>>>(abuf, pos1, W3 + 1024, S_B, csrB, c2, hp2);

    // ===== level C: conv4 (store), conv5 (fused pool_out) =====
    node_a_kernel<32, 64><<<N2 / 256, 256, 0, stream>>>(hp2, pos2, W4, b4, abuf, N2);
    gather4_kernel<64, 0, 512, 1><<<N2, 512, 0, stream>>>(abuf, pos2, W4 + 2048, SC, csrC, nullptr, h4);
    node_a_kernel<64, 64><<<N2 / 256, 256, 0, stream>>>(h4, pos2, W5, b5, abuf, N2);
    cellout_kernel<<<N2 / 256, 256, 0, stream>>>(pos2, cell, N2);
    gather4_kernel<64, 1, 512, 1><<<N2, 512, 0, stream>>>(abuf, pos2, W5 + 4096, SC, csrC, cell, g);

    // ===== MLP head =====
    mlp1_kernel<<<dim3(32, 8), 256, 0, stream>>>(g, Wl1, hid);
    mlp2_kernel<<<32, 64, 0, stream>>>(hid, bl1, Wl2, bl2, out);
}

// Round 8
// 510.435 us; speedup vs baseline: 2.3112x; 1.3050x over previous
//
#include <hip/hip_runtime.h>
#include <cstdint>
#include <cstddef>

#define B_GRAPHS 32
#define NPG      8192
#define N_NODES  (B_GRAPHS * NPG)   // 262144
#define DEG      8
#define NE       (N_NODES * DEG)    // 2097152
#define N1       32768              // B * 32*32  (grid 4)
#define N2       8192               // B * 16*16  (grid 8)
#define BKT_CAP  80
#define CPG      8                  // chunks per graph for parallel sorts

// ---------------------------------------------------------------------------
// Node-level precompute: a[i,o] = b[o] + sum_k h[i,k]*W[k,o] + px*W[IN,o] + py*W[IN+1,o]
// ---------------------------------------------------------------------------
template<int IN, int OUT>
__global__ __launch_bounds__(256)
void node_a_kernel(const float* __restrict__ h, const float* __restrict__ pos,
                   const float* __restrict__ W, const float* __restrict__ bias,
                   float* __restrict__ a, int n) {
    constexpr int FEAT = IN + 2;
    __shared__ float Ws[FEAT * OUT + OUT];
    for (int i = threadIdx.x; i < FEAT * OUT; i += 256) Ws[i] = W[i];
    for (int i = threadIdx.x; i < OUT; i += 256) Ws[FEAT * OUT + i] = bias[i];
    __syncthreads();
    int i = blockIdx.x * 256 + threadIdx.x;
    if (i >= n) return;

    float acc[OUT];
    #pragma unroll
    for (int o = 0; o < OUT; ++o) acc[o] = Ws[FEAT * OUT + o];

    float px = pos[i * 3 + 0], py = pos[i * 3 + 1];
    #pragma unroll
    for (int o = 0; o < OUT; ++o)
        acc[o] += px * Ws[IN * OUT + o] + py * Ws[(IN + 1) * OUT + o];

    if constexpr (IN % 4 == 0) {
        const float4* h4 = (const float4*)(h + (size_t)i * IN);
        for (int k4 = 0; k4 < IN / 4; ++k4) {
            float4 f = h4[k4];
            #pragma unroll
            for (int o = 0; o < OUT; ++o) {
                acc[o] += f.x * Ws[(k4 * 4 + 0) * OUT + o];
                acc[o] += f.y * Ws[(k4 * 4 + 1) * OUT + o];
                acc[o] += f.z * Ws[(k4 * 4 + 2) * OUT + o];
                acc[o] += f.w * Ws[(k4 * 4 + 3) * OUT + o];
            }
        }
    } else {
        for (int k = 0; k < IN; ++k) {
            float f = h[(size_t)i * IN + k];
            #pragma unroll
            for (int o = 0; o < OUT; ++o) acc[o] += f * Ws[k * OUT + o];
        }
    }
    float* ap = a + (size_t)i * OUT;
    #pragma unroll
    for (int o = 0; o < OUT; ++o) ap[o] = acc[o];
}

// ---------------------------------------------------------------------------
// Per-graph edge histogram (gcnt zeroed) + tiny serial scan.
// ---------------------------------------------------------------------------
__global__ __launch_bounds__(256)
void precount_kernel(const int* __restrict__ dst, int* __restrict__ gcnt) {
    __shared__ int hist[B_GRAPHS];
    if (threadIdx.x < B_GRAPHS) hist[threadIdx.x] = 0;
    __syncthreads();
    int gid = blockIdx.x * 256 + threadIdx.x;
    for (int e = gid; e < NE; e += 256 * 256)
        atomicAdd(&hist[dst[e] >> 13], 1);
    __syncthreads();
    if (threadIdx.x < B_GRAPHS) atomicAdd(&gcnt[threadIdx.x], hist[threadIdx.x]);
}

__global__ void gscan_kernel(const int* __restrict__ gcnt, int* __restrict__ gbase,
                             int* __restrict__ gcur) {
    if (threadIdx.x == 0) {
        int run = 0;
        for (int g = 0; g < B_GRAPHS; ++g) {
            gbase[g] = run; gcur[g] = run;
            run += gcnt[g];
        }
        gbase[B_GRAPHS] = run;
    }
}

// ---------------------------------------------------------------------------
// Bucket edges by graph, packed local (src<<13 | dst). Coalesced flushes.
// ---------------------------------------------------------------------------
__global__ __launch_bounds__(256)
void bucket_kernel(const int* __restrict__ src, const int* __restrict__ dst,
                   int* __restrict__ gcur, int* __restrict__ binned) {
    __shared__ int bins[B_GRAPHS][BKT_CAP];
    __shared__ int bcnt[B_GRAPHS], sbase[B_GRAPHS], sn[B_GRAPHS];
    int tid = threadIdx.x;
    if (tid < B_GRAPHS) bcnt[tid] = 0;
    __syncthreads();
    int wgbase = blockIdx.x * 2048;
    for (int sub = 0; sub < 2; ++sub) {
        int e0 = wgbase + sub * 1024 + tid * 4;
        int4 s4 = *(const int4*)&src[e0];
        int4 d4 = *(const int4*)&dst[e0];
        int ss[4] = {s4.x, s4.y, s4.z, s4.w};
        int dd[4] = {d4.x, d4.y, d4.z, d4.w};
        #pragma unroll
        for (int k = 0; k < 4; ++k) {
            int b = dd[k] >> 13;
            int pk = ((ss[k] & 8191) << 13) | (dd[k] & 8191);
            int pos = atomicAdd(&bcnt[b], 1);
            if (pos < BKT_CAP) bins[b][pos] = pk;
            else { int gp = atomicAdd(&gcur[b], 1); binned[gp] = pk; }
        }
        __syncthreads();
        if (tid < B_GRAPHS) {
            int nb = min(bcnt[tid], BKT_CAP);
            sn[tid] = nb;
            sbase[tid] = atomicAdd(&gcur[tid], nb);
        }
        __syncthreads();
        int b = tid >> 3, r = tid & 7;
        for (int k = r; k < sn[b]; k += 8) binned[sbase[b] + k] = bins[b][k];
        __syncthreads();
        if (tid < B_GRAPHS) bcnt[tid] = 0;
        __syncthreads();
    }
}

// ---------------------------------------------------------------------------
// Parallel chunked counting sort (hist -> global scan -> fill), 8 chunks/graph.
// LEVB 0: bin = dst_local>>4 (512 bins), keep all, value = packed edge.
// LEVB 1: bin = c1[dst] local (1024 bins), drop self-loops, value = c1[src] global.
// ---------------------------------------------------------------------------
template<int BINS, int LEVB>
__global__ __launch_bounds__(1024)
void sort_hist_kernel(const int* __restrict__ binned, const int* __restrict__ gbase,
                      const int* __restrict__ gend, const int* __restrict__ c1,
                      int* __restrict__ H) {
    __shared__ int hist[BINS];
    int wg = blockIdx.x, g = wg >> 3, sub = wg & 7, t = threadIdx.x;
    for (int i = t; i < BINS; i += 1024) hist[i] = 0;
    __syncthreads();
    int segb = gbase[g], sege = gend[g];
    int csz = (sege - segb + CPG - 1) / CPG;
    int e0 = segb + sub * csz, e1 = min(e0 + csz, sege);
    int nodeb = g * NPG;
    for (int e = e0 + t; e < e1; e += 1024) {
        int pk = binned[e];
        if (LEVB) {
            int sc = c1[nodeb + (pk >> 13)];
            int dc = c1[nodeb + (pk & 8191)];
            if (sc != dc) atomicAdd(&hist[dc & (BINS - 1)], 1);
        } else {
            atomicAdd(&hist[(pk & 8191) >> 4], 1);
        }
    }
    __syncthreads();
    for (int b = t; b < BINS; b += 1024)
        H[(size_t)(g * BINS + b) * CPG + sub] = hist[b];
}

template<int BINS, int LEVB>
__global__ __launch_bounds__(1024)
void sort_fill_kernel(const int* __restrict__ binned, const int* __restrict__ gbase,
                      const int* __restrict__ gend, const int* __restrict__ c1,
                      const int* __restrict__ S, int* __restrict__ outv) {
    __shared__ int cur[BINS];
    int wg = blockIdx.x, g = wg >> 3, sub = wg & 7, t = threadIdx.x;
    for (int b = t; b < BINS; b += 1024)
        cur[b] = S[(size_t)(g * BINS + b) * CPG + sub];
    __syncthreads();
    int segb = gbase[g], sege = gend[g];
    int csz = (sege - segb + CPG - 1) / CPG;
    int e0 = segb + sub * csz, e1 = min(e0 + csz, sege);
    int nodeb = g * NPG;
    for (int e = e0 + t; e < e1; e += 1024) {
        int pk = binned[e];
        if (LEVB) {
            int sc = c1[nodeb + (pk >> 13)];
            int dc = c1[nodeb + (pk & 8191)];
            if (sc != dc) {
                int p = atomicAdd(&cur[dc & (BINS - 1)], 1);
                outv[p] = sc;
            }
        } else {
            int p = atomicAdd(&cur[(pk & 8191) >> 4], 1);
            outv[p] = pk;
        }
    }
}

// ---------------------------------------------------------------------------
// Hierarchical exclusive scan (n % 1024 == 0, n/1024 <= 256).
// ---------------------------------------------------------------------------
__global__ __launch_bounds__(256)
void scan_reduce_kernel(const int* __restrict__ counts, int* __restrict__ blocksums) {
    int t = threadIdx.x;
    int4 v = *(const int4*)&counts[blockIdx.x * 1024 + t * 4];
    int s = v.x + v.y + v.z + v.w;
    #pragma unroll
    for (int off = 32; off > 0; off >>= 1) s += __shfl_xor(s, off, 64);
    __shared__ int ws[4];
    if ((t & 63) == 0) ws[t >> 6] = s;
    __syncthreads();
    if (t == 0) blocksums[blockIdx.x] = ws[0] + ws[1] + ws[2] + ws[3];
}

__global__ __launch_bounds__(256)
void scan_blocks_kernel(const int* __restrict__ blocksums, int* __restrict__ blockpref,
                        int* __restrict__ offsets, int nb, int n) {
    __shared__ int sh[256];
    int t = threadIdx.x;
    int v = (t < nb) ? blocksums[t] : 0;
    sh[t] = v;
    __syncthreads();
    #pragma unroll
    for (int d = 1; d < 256; d <<= 1) {
        int u = (t >= d) ? sh[t - d] : 0;
        __syncthreads();
        sh[t] += u;
        __syncthreads();
    }
    if (t < nb) blockpref[t] = sh[t] - v;
    if (t == 255) offsets[n] = sh[255];
}

__global__ __launch_bounds__(256)
void scan_write_kernel(const int* __restrict__ counts, const int* __restrict__ blockpref,
                       int* __restrict__ offsets, int* __restrict__ cursor) {
    int b = blockIdx.x, t = threadIdx.x;
    int base = b * 1024 + t * 4;
    int4 v = *(const int4*)&counts[base];
    int s = v.x + v.y + v.z + v.w;
    __shared__ int sh[256];
    sh[t] = s;
    __syncthreads();
    #pragma unroll
    for (int d = 1; d < 256; d <<= 1) {
        int u = (t >= d) ? sh[t - d] : 0;
        __syncthreads();
        sh[t] += u;
        __syncthreads();
    }
    int pref = blockpref[b] + sh[t] - s;
    int4 o;
    o.x = pref;
    o.y = pref + v.x;
    o.z = o.y + v.y;
    o.w = o.z + v.z;
    *(int4*)&offsets[base] = o;
    if (cursor) *(int4*)&cursor[base] = o;
}

// ---------------------------------------------------------------------------
// Level-A fused conv1+pool1: one wg per 16-dst bucket; per-(dst,ch) LDS
// atomicMax slots with order-preserving uint keys. XCD-swizzled blockIdx.
// ---------------------------------------------------------------------------
__global__ __launch_bounds__(256)
void gatherA_kernel(const float* __restrict__ a, const float* __restrict__ pos,
                    const float* __restrict__ Wp, const int* __restrict__ S,
                    const int* __restrict__ sortedA, const int* __restrict__ c1,
                    float* __restrict__ hp1) {
    __shared__ unsigned slot[256];
    int bid = blockIdx.x;
    int v = (bid & 7) * (B_GRAPHS * 512 / 8) + (bid >> 3);   // XCD-contiguous graphs
    int g = v >> 9;
    int t = threadIdx.x;
    slot[t] = 0u;
    __syncthreads();
    int start = S[(size_t)v * CPG], end = S[(size_t)(v + 1) * CPG];
    int nodeb = g * NPG;
    int ch = t & 15, el = t >> 4;
    for (int j = start + el; j < end; j += 16) {
        int pk = sortedA[j];
        float val = a[(size_t)(nodeb + (pk >> 13)) * 16 + ch];
        unsigned u = __float_as_uint(val);
        unsigned key = (u & 0x80000000u) ? ~u : (u | 0x80000000u);
        atomicMax(&slot[((pk & 15) << 4) + ch], key);
    }
    __syncthreads();
    int dl = t >> 4;
    unsigned k = slot[(dl << 4) + ch];
    if (k) {
        unsigned u = (k & 0x80000000u) ? (k ^ 0x80000000u) : ~k;
        float m = __uint_as_float(u);
        int dst = nodeb + ((v & 511) << 4) + dl;
        float px = pos[dst * 3 + 0], py = pos[dst * 3 + 1];
        float val = fmaxf(m - (px * Wp[ch] + py * Wp[16 + ch]), 0.0f);
        if (val > 0.0f)
            atomicMax((int*)&hp1[(size_t)c1[dst] * 16 + ch], __float_as_int(val));
    }
}

// ---------------------------------------------------------------------------
// Level-C dedupe bitmap (parallel): LDS bitmap per chunk, merge via atomicOr.
// ---------------------------------------------------------------------------
__global__ __launch_bounds__(1024)
void bitC_kernel(const int* __restrict__ binned, const int* __restrict__ gbase,
                 const int* __restrict__ gend, const int* __restrict__ c12,
                 unsigned* __restrict__ bitsG) {
    __shared__ unsigned bits[2048];
    int wg = blockIdx.x, g = wg >> 3, sub = wg & 7, t = threadIdx.x;
    for (int i = t; i < 2048; i += 1024) bits[i] = 0;
    __syncthreads();
    int segb = gbase[g], sege = gend[g];
    int csz = (sege - segb + CPG - 1) / CPG;
    int e0 = segb + sub * csz, e1 = min(e0 + csz, sege);
    int nodeb = g * NPG, clb = g * 256;
    for (int e = e0 + t; e < e1; e += 1024) {
        int pk = binned[e];
        int sc = c12[nodeb + (pk >> 13)] - clb;
        int dc = c12[nodeb + (pk & 8191)] - clb;
        if (sc != dc) atomicOr(&bits[(dc << 3) + (sc >> 5)], 1u << (sc & 31));
    }
    __syncthreads();
    for (int i = t; i < 2048; i += 1024) {
        unsigned wv = bits[i];
        if (wv) atomicOr(&bitsG[((size_t)g << 11) + i], wv);
    }
}

__global__ __launch_bounds__(256)
void popcC_kernel(const unsigned* __restrict__ bitsG, int* __restrict__ pc) {
    int i = blockIdx.x * 256 + threadIdx.x;
    int s = 0;
    #pragma unroll
    for (int k = 0; k < 8; ++k) s += __popc(bitsG[((size_t)i << 3) + k]);
    pc[i] = s;
}

__global__ __launch_bounds__(256)
void emitC_kernel(const unsigned* __restrict__ bitsG, const int* __restrict__ SC,
                  int* __restrict__ csrC) {
    int i = blockIdx.x * 256 + threadIdx.x;
    int clb = (i >> 8) << 8;
    int p = SC[i];
    #pragma unroll
    for (int w = 0; w < 8; ++w) {
        unsigned word = bitsG[((size_t)i << 3) + w];
        while (word) {
            int b = __ffs(word) - 1;
            word &= word - 1;
            csrC[p++] = clb + (w << 5) + b;
        }
    }
}

// ---------------------------------------------------------------------------
// Coarse gather-max conv (wave per node, float4 channels, XCD-swizzled):
// lane = (edge_stream s, ch4); OUT=32 -> 8 streams, OUT=64 -> 4 streams.
// 8 nodes per 512-thread block => many independent latency chains per CU.
// MODE 0: store; MODE 1: atomicMax into out[outmap[v]] (vals >= 0, 0-init).
// ---------------------------------------------------------------------------
template<int OUT, int MODE, int STRIDE>
__global__ __launch_bounds__(512)
void gatherR_kernel(const float* __restrict__ a, const float* __restrict__ pos,
                    const float* __restrict__ Wp, const int* __restrict__ S,
                    const int* __restrict__ csr, const int* __restrict__ outmap,
                    float* __restrict__ out, int nblocks) {
    constexpr int CH4 = OUT / 4;          // float4-lanes per edge
    constexpr int ES  = 64 / CH4;         // edge streams per wave
    int bid = blockIdx.x;
    int sb = (bid & 7) * (nblocks >> 3) + (bid >> 3);   // XCD-contiguous ranges
    int v = sb * 8 + (threadIdx.x >> 6);
    int lane = threadIdx.x & 63;
    int ch4 = lane % CH4, s = lane / CH4;
    int l = S[(size_t)v * STRIDE], h = S[(size_t)(v + 1) * STRIDE];
    float4 m = make_float4(-1e30f, -1e30f, -1e30f, -1e30f);
    for (int j = l + s; j < h; j += ES) {
        int sc = csr[j];
        float4 f = *(const float4*)&a[(size_t)sc * OUT + ch4 * 4];
        m.x = fmaxf(m.x, f.x); m.y = fmaxf(m.y, f.y);
        m.z = fmaxf(m.z, f.z); m.w = fmaxf(m.w, f.w);
    }
    #pragma unroll
    for (int st = CH4; st < 64; st <<= 1) {
        m.x = fmaxf(m.x, __shfl_xor(m.x, st, 64));
        m.y = fmaxf(m.y, __shfl_xor(m.y, st, 64));
        m.z = fmaxf(m.z, __shfl_xor(m.z, st, 64));
        m.w = fmaxf(m.w, __shfl_xor(m.w, st, 64));
    }
    if (s == 0) {
        float px = pos[v * 3 + 0], py = pos[v * 3 + 1];
        float4 wx = *(const float4*)&Wp[ch4 * 4];
        float4 wy = *(const float4*)&Wp[OUT + ch4 * 4];
        bool ne = h > l;
        float4 val;
        val.x = ne ? fmaxf(m.x - (px * wx.x + py * wy.x), 0.0f) : 0.0f;
        val.y = ne ? fmaxf(m.y - (px * wx.y + py * wy.y), 0.0f) : 0.0f;
        val.z = ne ? fmaxf(m.z - (px * wx.z + py * wy.z), 0.0f) : 0.0f;
        val.w = ne ? fmaxf(m.w - (px * wx.w + py * wy.w), 0.0f) : 0.0f;
        if (MODE == 0) {
            *(float4*)&out[(size_t)v * OUT + ch4 * 4] = val;
        } else {
            int base = outmap[v] * OUT + ch4 * 4;
            if (val.x > 0.0f) atomicMax((int*)&out[base + 0], __float_as_int(val.x));
            if (val.y > 0.0f) atomicMax((int*)&out[base + 1], __float_as_int(val.y));
            if (val.z > 0.0f) atomicMax((int*)&out[base + 2], __float_as_int(val.z));
            if (val.w > 0.0f) atomicMax((int*)&out[base + 3], __float_as_int(val.w));
        }
    }
}

// ---------------------------------------------------------------------------
// Voxel cluster id + pos mean accumulation; finalize; out-cells; c12 compose.
// ---------------------------------------------------------------------------
__global__ __launch_bounds__(256)
void cluster_kernel(const float* __restrict__ pos, int* __restrict__ cluster,
                    float* __restrict__ psum, int* __restrict__ cnt,
                    int n, int batch_shift, float inv_grid, int cells) {
    int i = blockIdx.x * 256 + threadIdx.x;
    if (i >= n) return;
    float px = pos[i * 3 + 0], py = pos[i * 3 + 1], pz = pos[i * 3 + 2];
    int ix = min(max((int)floorf(px * inv_grid), 0), cells - 1);
    int iy = min(max((int)floorf(py * inv_grid), 0), cells - 1);
    int c = (i >> batch_shift) * cells * cells + iy * cells + ix;
    cluster[i] = c;
    atomicAdd(&psum[c * 3 + 0], px);
    atomicAdd(&psum[c * 3 + 1], py);
    atomicAdd(&psum[c * 3 + 2], pz);
    atomicAdd(&cnt[c], 1);
}

__global__ __launch_bounds__(256)
void posfin_kernel(const float* __restrict__ pos_sum, const int* __restrict__ cnt,
                   float* __restrict__ pos_new, int n_new) {
    int i = blockIdx.x * 256 + threadIdx.x;
    if (i >= n_new) return;
    float c = fmaxf((float)cnt[i], 1.0f);
    pos_new[i * 3 + 0] = pos_sum[i * 3 + 0] / c;
    pos_new[i * 3 + 1] = pos_sum[i * 3 + 1] / c;
    pos_new[i * 3 + 2] = pos_sum[i * 3 + 2] / c;
}

__global__ __launch_bounds__(256)
void cellout_kernel(const float* __restrict__ pos, int* __restrict__ cell, int n) {
    int i = blockIdx.x * 256 + threadIdx.x;
    if (i >= n) return;
    float px = pos[i * 3 + 0], py = pos[i * 3 + 1];
    int ix = min(max((int)floorf(px * (1.0f / 16.0f)), 0), 7);
    int iy = min(max((int)floorf(py * (1.0f / 16.0f)), 0), 7);
    cell[i] = (i >> 8) * 64 + iy * 8 + ix;
}

__global__ __launch_bounds__(256)
void c12map_kernel(const int* __restrict__ c1, const int* __restrict__ c2,
                   int* __restrict__ c12) {
    int i = blockIdx.x * 256 + threadIdx.x;
    if (i < N_NODES) c12[i] = c2[c1[i]];
}

// ---------------------------------------------------------------------------
// MLP head
// ---------------------------------------------------------------------------
__global__ __launch_bounds__(256)
void mlp1_kernel(const float* __restrict__ g, const float* __restrict__ Wl1,
                 float* __restrict__ hid) {
    int b = blockIdx.x, kc = blockIdx.y, t = threadIdx.x;
    const float* grow = g + (size_t)b * 4096;
    int o0 = t * 4;
    float a0 = 0, a1 = 0, a2 = 0, a3 = 0;
    int k0 = kc * 512;
    for (int k = k0; k < k0 + 512; ++k) {
        float gk = grow[k];
        float4 w = *(const float4*)&Wl1[(size_t)k * 1024 + o0];
        a0 += gk * w.x; a1 += gk * w.y; a2 += gk * w.z; a3 += gk * w.w;
    }
    float* hp = hid + (size_t)b * 1024 + o0;
    atomicAdd(hp + 0, a0);
    atomicAdd(hp + 1, a1);
    atomicAdd(hp + 2, a2);
    atomicAdd(hp + 3, a3);
}

__global__ __launch_bounds__(64)
void mlp2_kernel(const float* __restrict__ hid, const float* __restrict__ bl1,
                 const float* __restrict__ Wl2, const float* __restrict__ bl2,
                 float* __restrict__ out) {
    int b = blockIdx.x, l = threadIdx.x;
    float hv[16];
    #pragma unroll
    for (int i = 0; i < 16; ++i) {
        int idx = l + i * 64;
        hv[i] = fmaxf(hid[(size_t)b * 1024 + idx] + bl1[idx], 0.0f);
    }
    float logits[10];
    #pragma unroll
    for (int c = 0; c < 10; ++c) {
        float p = 0.0f;
        #pragma unroll
        for (int i = 0; i < 16; ++i)
            p += hv[i] * Wl2[(size_t)(l + i * 64) * 10 + c];
        #pragma unroll
        for (int off = 32; off > 0; off >>= 1) p += __shfl_xor(p, off, 64);
        logits[c] = p + bl2[c];
    }
    float m = logits[0];
    #pragma unroll
    for (int c = 1; c < 10; ++c) m = fmaxf(m, logits[c]);
    float ssum = 0.0f;
    #pragma unroll
    for (int c = 0; c < 10; ++c) ssum += expf(logits[c] - m);
    float lse = logf(ssum);
    if (l < 10) out[b * 10 + l] = logits[l] - m - lse;
}

// ---------------------------------------------------------------------------
extern "C" void kernel_launch(void* const* d_in, const int* in_sizes, int n_in,
                              void* d_out, int out_size, void* d_ws, size_t ws_size,
                              hipStream_t stream) {
    const float* x    = (const float*)d_in[0];
    const float* pos0 = (const float*)d_in[1];
    const int*   ei   = (const int*)d_in[2];
    const float* W1 = (const float*)d_in[4];  const float* b1 = (const float*)d_in[5];
    const float* W2 = (const float*)d_in[6];  const float* b2 = (const float*)d_in[7];
    const float* W3 = (const float*)d_in[8];  const float* b3 = (const float*)d_in[9];
    const float* W4 = (const float*)d_in[10]; const float* b4 = (const float*)d_in[11];
    const float* W5 = (const float*)d_in[12]; const float* b5 = (const float*)d_in[13];
    const float* Wl1 = (const float*)d_in[14]; const float* bl1 = (const float*)d_in[15];
    const float* Wl2 = (const float*)d_in[16]; const float* bl2 = (const float*)d_in[17];
    const int* src0 = ei;
    const int* dst0 = ei + NE;
    float* out = (float*)d_out;

    float* w = (float*)d_ws;
    size_t off = 0;
    auto alloc = [&](size_t n) { float* p = w + off; off += (n + 3) & ~(size_t)3; return p; };

    // --- zero-init region (one memset) ---
    int*      gcnt  = (int*)alloc(32);
    unsigned* bitsG = (unsigned*)alloc(B_GRAPHS * 2048);
    float* hp1   = alloc((size_t)N1 * 16);
    float* psum1 = alloc((size_t)N1 * 3);
    int*   icnt1 = (int*)alloc(N1);
    float* hp2   = alloc((size_t)N2 * 32);
    float* psum2 = alloc((size_t)N2 * 3);
    int*   icnt2 = (int*)alloc(N2);
    float* g     = alloc((size_t)B_GRAPHS * 4096);
    float* hid   = alloc((size_t)B_GRAPHS * 1024);
    size_t zero_bytes = off * sizeof(float);
    // --- abuf (a at every level) ---
    float* abuf = alloc((size_t)N_NODES * 16);
    // --- union 1: binned (dead after bitC) -> h2, h4 ---
    float* ubase = alloc((size_t)NE);
    int*   binned = (int*)ubase;
    float* h2 = ubase;
    float* h4 = h2 + (size_t)N1 * 32;
    // --- union 2: sortedA (dead after gatherA) -> csrC ---
    int* sortedA = (int*)alloc(NE);
    int* csrC = sortedA;
    // --- rest ---
    int* csrB = (int*)alloc(NE);
    int* H   = (int*)alloc((size_t)B_GRAPHS * 1024 * CPG + 4);
    int* S_A = (int*)alloc((size_t)B_GRAPHS * 512 * CPG + 4);
    int* S_B = (int*)alloc((size_t)B_GRAPHS * 1024 * CPG + 4);
    int* pc  = (int*)alloc(N2);
    int* SC  = (int*)alloc(N2 + 4);
    float* pos1 = alloc((size_t)N1 * 3);
    float* pos2 = alloc((size_t)N2 * 3);
    int* cell = (int*)alloc(N2);
    int* c1   = (int*)alloc(N_NODES);
    int* c2   = (int*)alloc(N1);
    int* c12  = (int*)alloc(N_NODES);
    int* gbase = (int*)alloc(64);
    int* gcur  = (int*)alloc(64);
    int* blocksums = (int*)alloc(512);
    int* blockpref = (int*)alloc(512);
    (void)ws_size; (void)in_sizes; (void)n_in; (void)out_size;

    hipMemsetAsync(d_ws, 0, zero_bytes, stream);

    auto hscan = [&](const int* cnts, int* offs, int n) {
        scan_reduce_kernel<<<n / 1024, 256, 0, stream>>>(cnts, blocksums);
        scan_blocks_kernel<<<1, 256, 0, stream>>>(blocksums, blockpref, offs, n / 1024, n);
        scan_write_kernel<<<n / 1024, 256, 0, stream>>>(cnts, blockpref, offs, nullptr);
    };

    // ===== level A: bucket by graph, bucket-16 sort, fused conv1+pool1 =====
    node_a_kernel<1, 16><<<N_NODES / 256, 256, 0, stream>>>(x, pos0, W1, b1, abuf, N_NODES);
    precount_kernel<<<256, 256, 0, stream>>>(dst0, gcnt);
    gscan_kernel<<<1, 64, 0, stream>>>(gcnt, gbase, gcur);
    bucket_kernel<<<NE / 2048, 256, 0, stream>>>(src0, dst0, gcur, binned);
    sort_hist_kernel<512, 0><<<B_GRAPHS * CPG, 1024, 0, stream>>>(binned, gbase, gcur, nullptr, H);
    hscan(H, S_A, B_GRAPHS * 512 * CPG);
    sort_fill_kernel<512, 0><<<B_GRAPHS * CPG, 1024, 0, stream>>>(binned, gbase, gcur, nullptr, S_A, sortedA);
    cluster_kernel<<<N_NODES / 256, 256, 0, stream>>>(pos0, c1, psum1, icnt1, N_NODES, 13, 0.25f, 32);
    gatherA_kernel<<<B_GRAPHS * 512, 256, 0, stream>>>(abuf, pos0, W1 + 16, S_A, sortedA, c1, hp1);
    posfin_kernel<<<N1 / 256, 256, 0, stream>>>(psum1, icnt1, pos1, N1);

    // ===== cluster maps =====
    cluster_kernel<<<N1 / 256, 256, 0, stream>>>(pos1, c2, psum2, icnt2, N1, 10, 0.125f, 16);
    posfin_kernel<<<N2 / 256, 256, 0, stream>>>(psum2, icnt2, pos2, N2);
    c12map_kernel<<<N_NODES / 256, 256, 0, stream>>>(c1, c2, c12);

    // ===== level-B CSR (1024-bin counting sort) =====
    sort_hist_kernel<1024, 1><<<B_GRAPHS * CPG, 1024, 0, stream>>>(binned, gbase, gcur, c1, H);
    hscan(H, S_B, B_GRAPHS * 1024 * CPG);
    sort_fill_kernel<1024, 1><<<B_GRAPHS * CPG, 1024, 0, stream>>>(binned, gbase, gcur, c1, S_B, csrB);

    // ===== level-C CSR (parallel bitmap dedupe) =====
    bitC_kernel<<<B_GRAPHS * CPG, 1024, 0, stream>>>(binned, gbase, gcur, c12, bitsG);
    popcC_kernel<<<N2 / 256, 256, 0, stream>>>(bitsG, pc);
    hscan(pc, SC, N2);
    emitC_kernel<<<N2 / 256, 256, 0, stream>>>(bitsG, SC, csrC);

    // ===== level B: conv2 (store), conv3 (fused pool2) =====
    node_a_kernel<16, 32><<<N1 / 256, 256, 0, stream>>>(hp1, pos1, W2, b2, abuf, N1);
    gatherR_kernel<32, 0, CPG><<<N1 / 8, 512, 0, stream>>>(abuf, pos1, W2 + 512, S_B, csrB, nullptr, h2, N1 / 8);
    node_a_kernel<32, 32><<<N1 / 256, 256, 0, stream>>>(h2, pos1, W3, b3, abuf, N1);
    gatherR_kernel<32, 1, CPG><<<N1 / 8, 512, 0, stream>>>(abuf, pos1, W3 + 1024, S_B, csrB, c2, hp2, N1 / 8);

    // ===== level C: conv4 (store), conv5 (fused pool_out) =====
    node_a_kernel<32, 64><<<N2 / 256, 256, 0, stream>>>(hp2, pos2, W4, b4, abuf, N2);
    gatherR_kernel<64, 0, 1><<<N2 / 8, 512, 0, stream>>>(abuf, pos2, W4 + 2048, SC, csrC, nullptr, h4, N2 / 8);
    node_a_kernel<64, 64><<<N2 / 256, 256, 0, stream>>>(h4, pos2, W5, b5, abuf, N2);
    cellout_kernel<<<N2 / 256, 256, 0, stream>>>(pos2, cell, N2);
    gatherR_kernel<64, 1, 1><<<N2 / 8, 512, 0, stream>>>(abuf, pos2, W5 + 4096, SC, csrC, cell, g, N2 / 8);

    // ===== MLP head =====
    mlp1_kernel<<<dim3(32, 8), 256, 0, stream>>>(g, Wl1, hid);
    mlp2_kernel<<<32, 64, 0, stream>>>(hid, bl1, Wl2, bl2, out);
}